// Round 6
// baseline (1284.339 us; speedup 1.0000x reference)
//
#include <hip/hip_runtime.h>
#include <math.h>
#include <stdint.h>

// Problem dims
#define B_    128
#define T_    250
#define IN_   700
#define INP_  704    // padded to 32 (22 k-tiles of 32)
#define H_    512
#define OUT_  20
#define BR_   4
#define HB_   2048   // H_*BR_
#define WARM_ 10
#define VTH_  1.0f
#define TC_   125    // timesteps per chunk (2 chunks x 125)
#define TP_   128    // padded timesteps per chunk (one m-block = one batch)
#define MP_   16384  // B_ * TP_  (padded GEMM M per chunk)

typedef __attribute__((ext_vector_type(8)))  _Float16 half8;
typedef __attribute__((ext_vector_type(4)))  float f32x4;
typedef __attribute__((ext_vector_type(16))) float f32x16;
typedef __attribute__((ext_vector_type(4)))  int i32x4;
typedef __attribute__((ext_vector_type(16))) int i32x16;
typedef const __attribute__((address_space(1))) void* gptr_t;
typedef __attribute__((address_space(3))) void* lptr_t;

#define SB0() __builtin_amdgcn_sched_barrier(0)

// ---------------- prep: split fp32 -> hi/lo fp16 planes (layer 1) ----------------
__global__ __launch_bounds__(256)
void w1prep_kernel(const float* __restrict__ W, const float* __restrict__ M,
                   _Float16* __restrict__ w0, _Float16* __restrict__ w1) {
    int i = blockIdx.x * 256 + threadIdx.x;           // over HB_*INP_
    if (i >= HB_ * INP_) return;
    int r = i / INP_, c = i - r * INP_;
    float v = (c < IN_) ? W[(size_t)r * IN_ + c] * M[(size_t)r * IN_ + c] : 0.f;
    _Float16 h0 = (_Float16)v;
    w0[i] = h0;
    w1[i] = (_Float16)(v - (float)h0);
}

// ---------------- prep: layer-2 weights -> 3 signed radix-256 i8 planes, scale 2^26 ----------------
__global__ __launch_bounds__(256)
void w2prep_kernel(const float* __restrict__ W, const float* __restrict__ M,
                   int8_t* __restrict__ p2, int8_t* __restrict__ p1,
                   int8_t* __restrict__ p0) {
    int i = blockIdx.x * 256 + threadIdx.x;           // over HB_*H_
    if (i >= HB_ * H_) return;
    float v = W[i] * M[i];
    int q = (int)lrintf(v * 67108864.f);              // |q| <= ~2.97e6
    int b0 = (int)(int8_t)(q & 0xFF);  q = (q - b0) >> 8;
    int b1 = (int)(int8_t)(q & 0xFF);  int b2 = (q - b1) >> 8;   // |b2| <= 46
    p0[i] = (int8_t)b0; p1[i] = (int8_t)b1; p2[i] = (int8_t)b2;
}

// ---------------- prep: readout weights -> hi/lo fp16 planes, n padded to 32 ----------------
__global__ __launch_bounds__(256)
void woprep_kernel(const float* __restrict__ Wo, _Float16* __restrict__ wo0,
                   _Float16* __restrict__ wo1) {
    int i = blockIdx.x * 256 + threadIdx.x;           // over 32*H_
    if (i >= 32 * H_) return;
    int n = i >> 9;
    float v = (n < OUT_) ? Wo[(size_t)n * H_ + (i & (H_ - 1))] : 0.f;
    _Float16 h0 = (_Float16)v;
    wo0[i] = h0;
    wo1[i] = (_Float16)(v - (float)h0);
}

// per-chunk x conversion -> t-padded rows: row r = bb*TP_ + tl, tl in [0,TP_);
// rows with tl >= TC_ (and cols >= IN_) are zero.
__global__ __launch_bounds__(256)
void convx_kernel(const float* __restrict__ x, _Float16* __restrict__ x0,
                  _Float16* __restrict__ x1, int t0) {
    int i = blockIdx.x * 256 + threadIdx.x;
    if (i >= MP_ * INP_) return;
    int r = i / INP_, c = i - r * INP_;
    int bb = r >> 7, tl = r & (TP_ - 1);
    float v = (tl < TC_ && c < IN_) ? x[((size_t)bb * T_ + t0 + tl) * IN_ + c] : 0.f;
    _Float16 h0 = (_Float16)v;
    x0[i] = h0;
    x1[i] = (_Float16)(v - (float)h0);
}

__global__ void zero_kernel(float* __restrict__ p, int n4) {
    int i = blockIdx.x * blockDim.x + threadIdx.x;
    if (i < n4) ((float4*)p)[i] = make_float4(0.f, 0.f, 0.f, 0.f);
}

// ---------------- L1 fused: 128x128 GEMM + LIF scan, 48 KB LDS (3 blocks/CU) ----------------
// A planes (x0,x1) single-buffered 16 KB via reg-staging (write-side swizzle);
// B planes (w0,w1) double-buffered 2x16 KB via global_load_lds (pre-swizzled src).
// Epilogue: cur tile staged+scanned in t-quarters of 32 rows (curS 16 KB, aliased
// over A region); scan state carries in registers. Math verbatim R4 (absmax 0).
__global__ __launch_bounds__(256)
void l1_fused_kernel(const _Float16* __restrict__ x0, const _Float16* __restrict__ x1,
                     const _Float16* __restrict__ w0, const _Float16* __restrict__ w1,
                     const float* __restrict__ bias,
                     float* __restrict__ dst, float* __restrict__ mst,
                     float* __restrict__ spst, int8_t* __restrict__ sout,
                     const float* __restrict__ tau_m, const float* __restrict__ tau_n) {
    __shared__ alignas(16) char SMEM[49152];
    // GEMM: A single buf 16 KB at 0 (A0 8K | A1 8K); B dbuf at 16K (per buf 16K: B0 8K | B1 8K)
    // epilogue alias: curS (f32 32x128 = 16 KB) at 0; sbuf (i8 128x32 = 4 KB) at 16K
    float*  curS = (float*)SMEM;
    int8_t* sbuf = (int8_t*)(SMEM + 16384);

    const int tid  = threadIdx.x;
    const int wave = tid >> 6, lane = tid & 63;
    const int bb = blockIdx.y;
    const int bm = bb * TP_, bn = blockIdx.x * 128;

    const int srow   = tid >> 2;
    const int chunk  = tid & 3;
    const int wchunk = chunk ^ ((srow >> 1) & 3);
    const size_t boff0 = (size_t)(bn + srow) * INP_ + wchunk * 8;   // pre-swizzled source
    const size_t boff1 = boff0 + (size_t)64 * INP_;
    const size_t aoff0 = (size_t)(bm + srow) * INP_ + chunk * 8;    // linear (swizzle on ds_write)
    const size_t aoff1 = aoff0 + (size_t)64 * INP_;

    const int wm = wave & 1, wn = wave >> 1;
    const int row = lane & 31;
    const int khq = lane >> 5;
    const int key = (lane >> 1) & 3;
    const int cK0 = ((0 + khq) ^ key) * 8;
    const int cK1 = ((2 + khq) ^ key) * 8;

    f32x16 acc[2][2] = {};
    int4 aR[4];

    auto stageB = [&](int kt, int base) {
        const int k0 = kt * 32;
        char* Sb = SMEM + 16384 + base;
        __builtin_amdgcn_global_load_lds((gptr_t)(w0 + boff0 + k0), (lptr_t)(Sb + wave * 1024),          16, 0, 0);
        __builtin_amdgcn_global_load_lds((gptr_t)(w0 + boff1 + k0), (lptr_t)(Sb + 4096  + wave * 1024),  16, 0, 0);
        __builtin_amdgcn_global_load_lds((gptr_t)(w1 + boff0 + k0), (lptr_t)(Sb + 8192  + wave * 1024),  16, 0, 0);
        __builtin_amdgcn_global_load_lds((gptr_t)(w1 + boff1 + k0), (lptr_t)(Sb + 12288 + wave * 1024),  16, 0, 0);
    };

    auto loadA = [&](int kt) {
        const int k0 = kt * 32;
        aR[0] = *(const int4*)(x0 + aoff0 + k0);
        aR[1] = *(const int4*)(x0 + aoff1 + k0);
        aR[2] = *(const int4*)(x1 + aoff0 + k0);
        aR[3] = *(const int4*)(x1 + aoff1 + k0);
    };

    auto writeA = [&]() {
        char* d = SMEM + srow * 64 + wchunk * 16;
        *(int4*)(d)         = aR[0];
        *(int4*)(d + 4096)  = aR[1];
        *(int4*)(d + 8192)  = aR[2];
        *(int4*)(d + 12288) = aR[3];
    };

    auto compute = [&](int bbase) {
        const _Float16* A0s = (const _Float16*)SMEM;
        const _Float16* A1s = (const _Float16*)(SMEM + 8192);
        const _Float16* B0b = (const _Float16*)(SMEM + 16384 + bbase);
        const _Float16* B1b = (const _Float16*)(SMEM + 16384 + bbase + 8192);
        half8 a0f[2][2], a1f[2][2], b0f[2][2], b1f[2][2];
#pragma unroll
        for (int mt = 0; mt < 2; mt++) {
            const _Float16* ar = &A0s[(wm * 64 + mt * 32 + row) * 32];
            a0f[mt][0] = *(const half8*)&ar[cK0];
            a0f[mt][1] = *(const half8*)&ar[cK1];
        }
#pragma unroll
        for (int nt = 0; nt < 2; nt++) {
            const _Float16* br = &B0b[(wn * 64 + nt * 32 + row) * 32];
            b0f[nt][0] = *(const half8*)&br[cK0];
            b0f[nt][1] = *(const half8*)&br[cK1];
        }
        __builtin_amdgcn_s_setprio(1);
#pragma unroll
        for (int ks = 0; ks < 2; ks++)
#pragma unroll
            for (int mt = 0; mt < 2; mt++)
#pragma unroll
                for (int nt = 0; nt < 2; nt++)
                    acc[mt][nt] = __builtin_amdgcn_mfma_f32_32x32x16_f16(
                        a0f[mt][ks], b0f[nt][ks], acc[mt][nt], 0, 0, 0);
        __builtin_amdgcn_s_setprio(0);
#pragma unroll
        for (int nt = 0; nt < 2; nt++) {
            const _Float16* br = &B1b[(wn * 64 + nt * 32 + row) * 32];
            b1f[nt][0] = *(const half8*)&br[cK0];
            b1f[nt][1] = *(const half8*)&br[cK1];
        }
        __builtin_amdgcn_s_setprio(1);
#pragma unroll
        for (int ks = 0; ks < 2; ks++)
#pragma unroll
            for (int mt = 0; mt < 2; mt++)
#pragma unroll
                for (int nt = 0; nt < 2; nt++)
                    acc[mt][nt] = __builtin_amdgcn_mfma_f32_32x32x16_f16(
                        a0f[mt][ks], b1f[nt][ks], acc[mt][nt], 0, 0, 0);
        __builtin_amdgcn_s_setprio(0);
#pragma unroll
        for (int mt = 0; mt < 2; mt++) {
            const _Float16* ar = &A1s[(wm * 64 + mt * 32 + row) * 32];
            a1f[mt][0] = *(const half8*)&ar[cK0];
            a1f[mt][1] = *(const half8*)&ar[cK1];
        }
        __builtin_amdgcn_s_setprio(1);
#pragma unroll
        for (int ks = 0; ks < 2; ks++)
#pragma unroll
            for (int mt = 0; mt < 2; mt++)
#pragma unroll
                for (int nt = 0; nt < 2; nt++)
                    acc[mt][nt] = __builtin_amdgcn_mfma_f32_32x32x16_f16(
                        a1f[mt][ks], b0f[nt][ks], acc[mt][nt], 0, 0, 0);
        __builtin_amdgcn_s_setprio(0);
    };

    // prologue: B(0) -> buf0; A(0) -> regs -> LDS
    stageB(0, 0);
    loadA(0);
    SB0();
    asm volatile("s_waitcnt vmcnt(0)" ::: "memory");
    writeA();
    asm volatile("s_waitcnt lgkmcnt(0)" ::: "memory");
    __builtin_amdgcn_s_barrier();

#pragma unroll 1
    for (int kt = 0; kt < INP_ / 32 - 1; kt++) {
        stageB(kt + 1, ((kt + 1) & 1) * 16384);
        loadA(kt + 1);
        SB0();
        compute((kt & 1) * 16384);
        __builtin_amdgcn_s_barrier();                       // all A-readers done
        asm volatile("s_waitcnt vmcnt(0)" ::: "memory");    // B(kt+1) staged, aR ready
        writeA();
        asm volatile("s_waitcnt lgkmcnt(0)" ::: "memory");
        __builtin_amdgcn_s_barrier();
    }
    compute(16384);   // kt = 21 (odd -> buf1)
    __syncthreads();  // GEMM fully done before LDS re-use

    // ---- epilogue: t-quarters of 32 rows; scan state carried in registers ----
    const int col = lane & 31;
    const int rb  = 4 * (lane >> 5);
    const int hg   = blockIdx.x * 32 + (tid & 31);
    const int sidx = bb * H_ + hg;
    float alpha = 0.f; float4 beta = {0.f, 0.f, 0.f, 0.f};
    float4 d = {0.f, 0.f, 0.f, 0.f};
    float m = 0.f, sp = 0.f;
    if (tid < 32) {
        alpha = 1.f / (1.f + expf(-tau_m[hg]));
        float4 tn = ((const float4*)tau_n)[hg];
        beta.x = 1.f / (1.f + expf(-tn.x));
        beta.y = 1.f / (1.f + expf(-tn.y));
        beta.z = 1.f / (1.f + expf(-tn.z));
        beta.w = 1.f / (1.f + expf(-tn.w));
        d  = ((const float4*)dst)[sidx];
        m  = mst[sidx];
        sp = spst[sidx];
    }
#pragma unroll 1
    for (int q = 0; q < 4; q++) {
        if (wm == (q >> 1)) {
            const int mt = q & 1;
#pragma unroll
            for (int nt = 0; nt < 2; nt++) {
                const int lcol = wn * 64 + nt * 32 + col;
                const float bv = bias[bn + lcol];
#pragma unroll
                for (int reg = 0; reg < 16; reg++) {
                    const int trow = (reg & 3) + 8 * (reg >> 2) + rb;   // 0..31 in quarter
                    curS[trow * 128 + lcol] = acc[mt][nt][reg] + bv;
                }
            }
        }
        __syncthreads();
        if (tid < 32) {
            const int t1 = min(TC_, (q + 1) * 32);
            for (int t = q * 32; t < t1; t++) {
                float4 c = ((const float4*)(curS + (t - q * 32) * 128))[tid];
                d.x = beta.x * d.x + (1.f - beta.x) * c.x;
                d.y = beta.y * d.y + (1.f - beta.y) * c.y;
                d.z = beta.z * d.z + (1.f - beta.z) * c.z;
                d.w = beta.w * d.w + (1.f - beta.w) * c.w;
                float s4 = ((d.x + d.y) + d.z) + d.w;
                m = m * alpha + (1.f - alpha) * s4 - VTH_ * sp;
                sp = (m > VTH_) ? 1.f : 0.f;
                sbuf[t * 32 + tid] = (int8_t)(m > VTH_);
            }
        }
        __syncthreads();
    }
    if (tid < 32) {
        sbuf[125 * 32 + tid] = 0; sbuf[126 * 32 + tid] = 0; sbuf[127 * 32 + tid] = 0;
        ((float4*)dst)[sidx] = d;
        mst[sidx] = m;
        spst[sidx] = sp;
    }
    __syncthreads();
    if (tid < TP_) {   // 32 B of spikes per padded-t row
        int4* dp = (int4*)&sout[((size_t)(bm + tid)) * H_ + blockIdx.x * 32];
        const int4* s4 = (const int4*)&sbuf[tid * 32];
        dp[0] = s4[0]; dp[1] = s4[1];
    }
}

// ---------------- L2 fused: i8 GEMM (R4 loop, 32 KB dbuf) + t-quartered LIF scan ----------------
__global__ __launch_bounds__(256)
void l2_fused_kernel(const int8_t* __restrict__ A,
                     const int8_t* __restrict__ p2, const int8_t* __restrict__ p1,
                     const int8_t* __restrict__ p0,
                     const float* __restrict__ bias,
                     float* __restrict__ dst, float* __restrict__ mst,
                     float* __restrict__ spst, _Float16* __restrict__ sout,
                     const float* __restrict__ tau_m, const float* __restrict__ tau_n) {
    __shared__ alignas(16) char SMEM[32768];      // GEMM dbuf 2x16 KB | epi: curS 16 KB at 0, sbuf 8 KB at 16K
    int8_t*   S    = (int8_t*)SMEM;
    float*    curS = (float*)SMEM;
    _Float16* sbuf = (_Float16*)(SMEM + 16384);

    const int tid  = threadIdx.x;
    const int wave = tid >> 6, lane = tid & 63;
    const int bb = blockIdx.y;
    const int bm = bb * TP_, bn = blockIdx.x * 128;

    const int    srow  = tid >> 2;
    const int    skoff = (((tid & 3) ^ ((srow >> 1) & 3)) * 16);   // pre-swizzled source
    const size_t aoff0 = (size_t)(bm + srow) * H_ + skoff;
    const size_t aoff1 = aoff0 + (size_t)64 * H_;
    const size_t boff0 = (size_t)(bn + srow) * H_ + skoff;
    const size_t boff1 = boff0 + (size_t)64 * H_;
    const int lo = wave * 1024;

    const int wm = wave & 1, wn = wave >> 1;
    const int row = lane & 31;
    const int khq = lane >> 5;
    const int key = (lane >> 1) & 3;
    const int cK0 = ((0 + khq) ^ key) * 16;
    const int cK1 = ((2 + khq) ^ key) * 16;

    i32x16 acc[2][2] = {};

    auto stage = [&](int i, int base) {
        const int s  = i >> 3;
        const int k0 = (i & 7) * 64;
        const int8_t* pw = (s == 0) ? p2 : (s == 1) ? p1 : p0;
        int8_t* Sb = S + base;
        __builtin_amdgcn_global_load_lds((gptr_t)(A  + aoff0 + k0), (lptr_t)(Sb + lo),          16, 0, 0);
        __builtin_amdgcn_global_load_lds((gptr_t)(A  + aoff1 + k0), (lptr_t)(Sb + 4096  + lo),  16, 0, 0);
        __builtin_amdgcn_global_load_lds((gptr_t)(pw + boff0 + k0), (lptr_t)(Sb + 8192  + lo),  16, 0, 0);
        __builtin_amdgcn_global_load_lds((gptr_t)(pw + boff1 + k0), (lptr_t)(Sb + 12288 + lo),  16, 0, 0);
    };

    auto compute = [&](int base) {
        const int8_t* Ab = S + base;
        const int8_t* Bb = Ab + 8192;
        i32x4 af[2][2], bf[2][2];
#pragma unroll
        for (int mt = 0; mt < 2; mt++) {
            const int8_t* ar = &Ab[(wm * 64 + mt * 32 + row) * 64];
            af[mt][0] = *(const i32x4*)&ar[cK0];
            af[mt][1] = *(const i32x4*)&ar[cK1];
        }
#pragma unroll
        for (int nt = 0; nt < 2; nt++) {
            const int8_t* br = &Bb[(wn * 64 + nt * 32 + row) * 64];
            bf[nt][0] = *(const i32x4*)&br[cK0];
            bf[nt][1] = *(const i32x4*)&br[cK1];
        }
        __builtin_amdgcn_s_setprio(1);
#pragma unroll
        for (int ks = 0; ks < 2; ks++)
#pragma unroll
            for (int mt = 0; mt < 2; mt++)
#pragma unroll
                for (int nt = 0; nt < 2; nt++)
                    acc[mt][nt] = __builtin_amdgcn_mfma_i32_32x32x32_i8(
                        af[mt][ks], bf[nt][ks], acc[mt][nt], 0, 0, 0);
        __builtin_amdgcn_s_setprio(0);
    };

    stage(0, 0);
    asm volatile("s_waitcnt vmcnt(0)" ::: "memory");
    __builtin_amdgcn_s_barrier();

    int cur = 0;
#pragma unroll 1
    for (int i = 0; i < 23; i++) {
        const int base = cur * 16384;
        stage(i + 1, base ^ 16384);
        if (i == 8 || i == 16) {
#pragma unroll
            for (int mt = 0; mt < 2; mt++)
#pragma unroll
                for (int nt = 0; nt < 2; nt++) acc[mt][nt] *= 256;  // exact, |acc|<1.6e9
        }
        compute(base);
        asm volatile("s_waitcnt vmcnt(0) lgkmcnt(0)" ::: "memory");
        __builtin_amdgcn_s_barrier();
        cur ^= 1;
    }
    compute(cur * 16384);
    __syncthreads();

    // ---- epilogue: t-quarters, verbatim math ----
    const float scale = 1.f / 67108864.f;
    const int col = lane & 31;
    const int rb  = 4 * (lane >> 5);
    const int hg   = blockIdx.x * 32 + (tid & 31);
    const int sidx = bb * H_ + hg;
    float alpha = 0.f; float4 beta = {0.f, 0.f, 0.f, 0.f};
    float4 d = {0.f, 0.f, 0.f, 0.f};
    float m = 0.f, sp = 0.f;
    if (tid < 32) {
        alpha = 1.f / (1.f + expf(-tau_m[hg]));
        float4 tn = ((const float4*)tau_n)[hg];
        beta.x = 1.f / (1.f + expf(-tn.x));
        beta.y = 1.f / (1.f + expf(-tn.y));
        beta.z = 1.f / (1.f + expf(-tn.z));
        beta.w = 1.f / (1.f + expf(-tn.w));
        d  = ((const float4*)dst)[sidx];
        m  = mst[sidx];
        sp = spst[sidx];
    }
#pragma unroll 1
    for (int q = 0; q < 4; q++) {
        if (wm == (q >> 1)) {
            const int mt = q & 1;
#pragma unroll
            for (int nt = 0; nt < 2; nt++) {
                const int lcol = wn * 64 + nt * 32 + col;
                const float bv = bias[bn + lcol];
#pragma unroll
                for (int reg = 0; reg < 16; reg++) {
                    const int trow = (reg & 3) + 8 * (reg >> 2) + rb;
                    curS[trow * 128 + lcol] = (float)acc[mt][nt][reg] * scale + bv;
                }
            }
        }
        __syncthreads();
        if (tid < 32) {
            const int t1 = min(TC_, (q + 1) * 32);
            for (int t = q * 32; t < t1; t++) {
                float4 c = ((const float4*)(curS + (t - q * 32) * 128))[tid];
                d.x = beta.x * d.x + (1.f - beta.x) * c.x;
                d.y = beta.y * d.y + (1.f - beta.y) * c.y;
                d.z = beta.z * d.z + (1.f - beta.z) * c.z;
                d.w = beta.w * d.w + (1.f - beta.w) * c.w;
                float s4 = ((d.x + d.y) + d.z) + d.w;
                m = m * alpha + (1.f - alpha) * s4 - VTH_ * sp;
                sp = (m > VTH_) ? 1.f : 0.f;
                sbuf[t * 32 + tid] = (_Float16)sp;
            }
        }
        __syncthreads();
    }
    if (tid < 32) {
        sbuf[125 * 32 + tid] = (_Float16)0.f;
        sbuf[126 * 32 + tid] = (_Float16)0.f;
        sbuf[127 * 32 + tid] = (_Float16)0.f;
        ((float4*)dst)[sidx] = d;
        mst[sidx] = m;
        spst[sidx] = sp;
    }
    __syncthreads();
    if (tid < TP_) {   // 64 B of f16 spikes per padded-t row
        int4* dp = (int4*)&sout[((size_t)(bm + tid)) * H_ + blockIdx.x * 32];
        const int4* s4 = (const int4*)&sbuf[tid * 32];
        dp[0] = s4[0]; dp[1] = s4[1]; dp[2] = s4[2]; dp[3] = s4[3];
    }
}

// ---------------- readout GEMM (MFMA 16x16): curo[b,t,o] = s2c . (wo0+wo1)^T + bo ----------------
// M = MP_ (t-padded); pad rows skipped at the store.
__global__ __launch_bounds__(256)
void rdot_mfma_kernel(const _Float16* __restrict__ s2c, const _Float16* __restrict__ wo0,
                      const _Float16* __restrict__ wo1, const float* __restrict__ bo,
                      float* __restrict__ curo, int t0) {
    __shared__ alignas(16) _Float16 S[2 * 6144];   // 24 KB: [buf][As 4096 | B0 1024 | B1 1024]
    const int tid  = threadIdx.x;
    const int wave = tid >> 6, lane = tid & 63;
    const int bm = blockIdx.x * 128;

    const int    srow  = tid >> 2;
    const int    skoff = (((tid & 3) ^ ((srow >> 1) & 3)) * 8);   // inverse-swizzled source
    const size_t aoff0 = (size_t)(bm + srow) * H_ + skoff;
    const size_t aoff1 = aoff0 + (size_t)64 * H_;
    const _Float16* bsrc = (wave < 2) ? wo0 : wo1;
    const int bw = wave & 1;
    const size_t boff = (size_t)(bw * 16 + (lane >> 2)) * H_
                      + ((lane & 3) ^ ((lane >> 3) & 3)) * 8;
    const int loA = wave * 512;
    const int loB = 4096 + (wave >> 1) * 1024 + bw * 512;

    const int fr = lane & 15;
    const int key = (lane >> 1) & 3;                 // = (fr>>1)&3
    const int cK  = (((lane >> 4) ^ key) * 8);       // swizzled k-column (halfs)

    f32x4 acc[2][2] = {};

    auto stage = [&](int kt, int base) {
        const int k0 = kt * 32;
        _Float16* Sb = S + base;
        __builtin_amdgcn_global_load_lds((gptr_t)(s2c + aoff0 + k0),  (lptr_t)(Sb + loA),        16, 0, 0);
        __builtin_amdgcn_global_load_lds((gptr_t)(s2c + aoff1 + k0),  (lptr_t)(Sb + 2048 + loA), 16, 0, 0);
        __builtin_amdgcn_global_load_lds((gptr_t)(bsrc + boff + k0),  (lptr_t)(Sb + loB),        16, 0, 0);
    };

    auto compute = [&](int base) {
        const _Float16* Ab  = S + base;
        const _Float16* B0b = Ab + 4096;
        const _Float16* B1b = Ab + 5120;
        half8 af[2], b0[2], b1[2];
#pragma unroll
        for (int mi = 0; mi < 2; mi++)
            af[mi] = *(const half8*)&Ab[(wave * 32 + mi * 16 + fr) * 32 + cK];
#pragma unroll
        for (int ni = 0; ni < 2; ni++) {
            b0[ni] = *(const half8*)&B0b[(ni * 16 + fr) * 32 + cK];
            b1[ni] = *(const half8*)&B1b[(ni * 16 + fr) * 32 + cK];
        }
        __builtin_amdgcn_s_setprio(1);
#pragma unroll
        for (int mi = 0; mi < 2; mi++)
#pragma unroll
            for (int ni = 0; ni < 2; ni++) {
                acc[mi][ni] = __builtin_amdgcn_mfma_f32_16x16x32_f16(af[mi], b0[ni], acc[mi][ni], 0, 0, 0);
                acc[mi][ni] = __builtin_amdgcn_mfma_f32_16x16x32_f16(af[mi], b1[ni], acc[mi][ni], 0, 0, 0);
            }
        __builtin_amdgcn_s_setprio(0);
    };

    stage(0, 0);
    asm volatile("s_waitcnt vmcnt(0)" ::: "memory");
    __builtin_amdgcn_s_barrier();

    int cur = 0;
    for (int kt = 0; kt < H_ / 32 - 1; kt++) {
        const int base = cur * 6144;
        stage(kt + 1, base ^ 6144);
        compute(base);
        asm volatile("s_waitcnt vmcnt(0) lgkmcnt(0)" ::: "memory");
        __builtin_amdgcn_s_barrier();
        cur ^= 1;
    }
    compute(cur * 6144);

    const int cc = lane & 15;
    const int cr = (lane >> 4) * 4;
#pragma unroll
    for (int ni = 0; ni < 2; ni++) {
        const int gc = ni * 16 + cc;
        if (gc < OUT_) {
            const float bv = bo[gc];
#pragma unroll
            for (int mi = 0; mi < 2; mi++) {
#pragma unroll
                for (int r = 0; r < 4; r++) {
                    const int gr = bm + wave * 32 + mi * 16 + cr + r;
                    const int bb = gr >> 7, tl = gr & (TP_ - 1);
                    if (tl < TC_)
                        curo[((size_t)bb * T_ + t0 + tl) * OUT_ + gc] = acc[mi][ni][r] + bv;
                }
            }
        }
    }
}

// ---------------- parallel readout: segmented scan + t-parallel softmax-sum ----------------
#define RT_SEG 12
#define RT_LEN 21   // 12*21 = 252 >= 250

__global__ __launch_bounds__(256)
void readout_kernel(const float* __restrict__ curo, const float* __restrict__ tau_mo,
                    float* __restrict__ out) {
    __shared__ float moS[T_ * OUT_];          // 20 KB
    __shared__ float segA[RT_SEG][OUT_];
    __shared__ float segU[RT_SEG][OUT_];
    __shared__ float pre[RT_SEG][OUT_];
    __shared__ float accS[OUT_];
    const int b = blockIdx.x;
    const int tid = threadIdx.x;
    const float* cb = curo + (size_t)b * T_ * OUT_;

    const int o = tid % OUT_;
    const int sg = tid / OUT_;
    const float ao = 1.f / (1.f + expf(-tau_mo[o]));

    if (tid < RT_SEG * OUT_) {
        int t0 = sg * RT_LEN;
        int t1 = min(T_, t0 + RT_LEN);
        float u = 0.f, Ap = 1.f;
        for (int t = t0; t < t1; t++) {
            u = ao * u + (1.f - ao) * cb[t * OUT_ + o];
            Ap *= ao;
        }
        segU[sg][o] = u; segA[sg][o] = Ap;
    }
    if (tid < OUT_) accS[tid] = 0.f;
    __syncthreads();
    if (tid < OUT_) {
        float m = 0.f;
        for (int s = 0; s < RT_SEG; s++) {
            pre[s][tid] = m;
            m = segA[s][tid] * m + segU[s][tid];
        }
    }
    __syncthreads();
    if (tid < RT_SEG * OUT_) {
        int t0 = sg * RT_LEN;
        int t1 = min(T_, t0 + RT_LEN);
        float m = pre[sg][o];
        for (int t = t0; t < t1; t++) {
            m = ao * m + (1.f - ao) * cb[t * OUT_ + o];
            moS[t * OUT_ + o] = m;
        }
    }
    __syncthreads();
    if (tid >= WARM_ + 1 && tid < T_) {
        int t = tid;
        float mx = -3.0e38f;
#pragma unroll
        for (int o2 = 0; o2 < OUT_; o2++) mx = fmaxf(mx, moS[t * OUT_ + o2]);
        float es[OUT_]; float se = 0.f;
#pragma unroll
        for (int o2 = 0; o2 < OUT_; o2++) {
            float e = expf(moS[t * OUT_ + o2] - mx);
            es[o2] = e; se += e;
        }
        float inv = 1.f / se;
#pragma unroll
        for (int o2 = 0; o2 < OUT_; o2++) atomicAdd(&accS[o2], es[o2] * inv);
    }
    __syncthreads();
    if (tid < OUT_) out[(size_t)b * OUT_ + tid] = accS[tid];
}

extern "C" void kernel_launch(void* const* d_in, const int* in_sizes, int n_in,
                              void* d_out, int out_size, void* d_ws, size_t ws_size,
                              hipStream_t stream) {
    const float* x      = (const float*)d_in[0];
    const float* W1     = (const float*)d_in[1];
    const float* b1     = (const float*)d_in[2];
    const float* tau_m1 = (const float*)d_in[3];
    const float* tau_n1 = (const float*)d_in[4];
    const float* mask1  = (const float*)d_in[5];
    const float* W2     = (const float*)d_in[6];
    const float* b2     = (const float*)d_in[7];
    const float* tau_m2 = (const float*)d_in[8];
    const float* tau_n2 = (const float*)d_in[9];
    const float* mask2  = (const float*)d_in[10];
    const float* Wo     = (const float*)d_in[11];
    const float* bo     = (const float*)d_in[12];
    const float* tau_mo = (const float*)d_in[13];
    float* out = (float*)d_out;

    // Fused-scan design: 2 chunks of 125 timesteps (padded to 128). ~86 MB.
    char* p = (char*)d_ws;
    auto alloc = [&](size_t bytes) { char* r = p; p += (bytes + 255) & ~(size_t)255; return r; };
    _Float16* w10 = (_Float16*)alloc((size_t)HB_ * INP_ * 2);
    _Float16* w11 = (_Float16*)alloc((size_t)HB_ * INP_ * 2);
    int8_t*   q2  = (int8_t*)alloc((size_t)HB_ * H_);
    int8_t*   q1  = (int8_t*)alloc((size_t)HB_ * H_);
    int8_t*   q0  = (int8_t*)alloc((size_t)HB_ * H_);
    _Float16* wo0 = (_Float16*)alloc((size_t)32 * H_ * 2);
    _Float16* wo1 = (_Float16*)alloc((size_t)32 * H_ * 2);
    _Float16* xc0 = (_Float16*)alloc((size_t)MP_ * INP_ * 2);
    _Float16* xc1 = (_Float16*)alloc((size_t)MP_ * INP_ * 2);
    int8_t*   s1c = (int8_t*)alloc((size_t)MP_ * H_);
    _Float16* s2c = (_Float16*)alloc((size_t)MP_ * H_ * 2);
    float* curo   = (float*)alloc((size_t)B_ * T_ * OUT_ * 4);
    float* st     = (float*)alloc((size_t)786432 * 4);
    float* d1  = st;
    float* m1  = d1 + (size_t)B_ * H_ * BR_;
    float* sp1 = m1 + (size_t)B_ * H_;
    float* d2  = sp1 + (size_t)B_ * H_;
    float* m2  = d2 + (size_t)B_ * H_ * BR_;
    float* sp2 = m2 + (size_t)B_ * H_;

    w1prep_kernel<<<(HB_ * INP_ + 255) / 256, 256, 0, stream>>>(W1, mask1, w10, w11);
    w2prep_kernel<<<(HB_ * H_ + 255) / 256, 256, 0, stream>>>(W2, mask2, q2, q1, q0);
    woprep_kernel<<<(32 * H_ + 255) / 256, 256, 0, stream>>>(Wo, wo0, wo1);
    zero_kernel<<<(786432 / 4 + 255) / 256, 256, 0, stream>>>(st, 786432 / 4);

    dim3 gg(HB_ / 128, B_);                 // (16 n-tiles, 128 batches)
    for (int c = 0; c < 2; c++) {
        const int t0 = c * TC_;
        convx_kernel<<<(MP_ * INP_) / 256, 256, 0, stream>>>(x, xc0, xc1, t0);
        l1_fused_kernel<<<gg, 256, 0, stream>>>(xc0, xc1, w10, w11, b1,
                                                d1, m1, sp1, s1c, tau_m1, tau_n1);
        l2_fused_kernel<<<gg, 256, 0, stream>>>(s1c, q2, q1, q0, b2,
                                                d2, m2, sp2, s2c, tau_m2, tau_n2);
        rdot_mfma_kernel<<<MP_ / 128, 256, 0, stream>>>(s2c, wo0, wo1, bo, curo, t0);
    }
    readout_kernel<<<B_, 256, 0, stream>>>(curo, tau_mo, out);
}

// Round 7
// 1029.758 us; speedup vs baseline: 1.2472x; 1.2472x over previous
//
#include <hip/hip_runtime.h>
#include <math.h>
#include <stdint.h>

// Problem dims
#define B_    128
#define T_    250
#define IN_   700
#define INP_  704    // padded to 32 (22 k-tiles of 32)
#define H_    512
#define OUT_  20
#define BR_   4
#define HB_   2048   // H_*BR_
#define WARM_ 10
#define VTH_  1.0f
#define TC_   125    // timesteps per chunk (2 chunks x 125)
#define TP_   128    // padded timesteps per chunk (one m-block = one batch)
#define MP_   16384  // B_ * TP_  (padded GEMM M per chunk)

typedef __attribute__((ext_vector_type(8)))  _Float16 half8;
typedef __attribute__((ext_vector_type(4)))  float f32x4;
typedef __attribute__((ext_vector_type(16))) float f32x16;
typedef __attribute__((ext_vector_type(4)))  int i32x4;
typedef __attribute__((ext_vector_type(16))) int i32x16;
typedef const __attribute__((address_space(1))) void* gptr_t;
typedef __attribute__((address_space(3))) void* lptr_t;

#define SB0() __builtin_amdgcn_sched_barrier(0)

// ---------------- prep: split fp32 -> hi/lo fp16 planes (layer 1) ----------------
__global__ __launch_bounds__(256)
void w1prep_kernel(const float* __restrict__ W, const float* __restrict__ M,
                   _Float16* __restrict__ w0, _Float16* __restrict__ w1) {
    int i = blockIdx.x * 256 + threadIdx.x;           // over HB_*INP_
    if (i >= HB_ * INP_) return;
    int r = i / INP_, c = i - r * INP_;
    float v = (c < IN_) ? W[(size_t)r * IN_ + c] * M[(size_t)r * IN_ + c] : 0.f;
    _Float16 h0 = (_Float16)v;
    w0[i] = h0;
    w1[i] = (_Float16)(v - (float)h0);
}

// ---------------- prep: layer-2 weights -> 3 signed radix-256 i8 planes, scale 2^26 ----------------
__global__ __launch_bounds__(256)
void w2prep_kernel(const float* __restrict__ W, const float* __restrict__ M,
                   int8_t* __restrict__ p2, int8_t* __restrict__ p1,
                   int8_t* __restrict__ p0) {
    int i = blockIdx.x * 256 + threadIdx.x;           // over HB_*H_
    if (i >= HB_ * H_) return;
    float v = W[i] * M[i];
    int q = (int)lrintf(v * 67108864.f);              // |q| <= ~2.97e6
    int b0 = (int)(int8_t)(q & 0xFF);  q = (q - b0) >> 8;
    int b1 = (int)(int8_t)(q & 0xFF);  int b2 = (q - b1) >> 8;   // |b2| <= 46
    p0[i] = (int8_t)b0; p1[i] = (int8_t)b1; p2[i] = (int8_t)b2;
}

// ---------------- prep: readout weights -> hi/lo fp16 planes, n padded to 32 ----------------
__global__ __launch_bounds__(256)
void woprep_kernel(const float* __restrict__ Wo, _Float16* __restrict__ wo0,
                   _Float16* __restrict__ wo1) {
    int i = blockIdx.x * 256 + threadIdx.x;           // over 32*H_
    if (i >= 32 * H_) return;
    int n = i >> 9;
    float v = (n < OUT_) ? Wo[(size_t)n * H_ + (i & (H_ - 1))] : 0.f;
    _Float16 h0 = (_Float16)v;
    wo0[i] = h0;
    wo1[i] = (_Float16)(v - (float)h0);
}

// per-chunk x conversion -> t-padded rows: row r = bb*TP_ + tl, tl in [0,TP_);
// rows with tl >= TC_ (and cols >= IN_) are zero.
__global__ __launch_bounds__(256)
void convx_kernel(const float* __restrict__ x, _Float16* __restrict__ x0,
                  _Float16* __restrict__ x1, int t0) {
    int i = blockIdx.x * 256 + threadIdx.x;
    if (i >= MP_ * INP_) return;
    int r = i / INP_, c = i - r * INP_;
    int bb = r >> 7, tl = r & (TP_ - 1);
    float v = (tl < TC_ && c < IN_) ? x[((size_t)bb * T_ + t0 + tl) * IN_ + c] : 0.f;
    _Float16 h0 = (_Float16)v;
    x0[i] = h0;
    x1[i] = (_Float16)(v - (float)h0);
}

__global__ void zero_kernel(float* __restrict__ p, int n4) {
    int i = blockIdx.x * blockDim.x + threadIdx.x;
    if (i < n4) ((float4*)p)[i] = make_float4(0.f, 0.f, 0.f, 0.f);
}

// ---------------- L1 fused: 128x128 GEMM + LIF scan, 48 KB LDS (3 blocks/CU) ----------------
// A planes (x0,x1) single-buffered 16 KB via reg-staging (write-side swizzle);
// B planes (w0,w1) double-buffered 2x16 KB via global_load_lds (pre-swizzled src).
// Epilogue: cur tile staged+scanned in t-quarters of 32 rows (curS 16 KB, aliased);
// q-loop FULLY UNROLLED so every acc index is compile-time (rule #20 — the R6
// `#pragma unroll 1` variant demoted acc to scratch: VGPR 68, 1 GB scratch writes).
__global__ __launch_bounds__(256)
void l1_fused_kernel(const _Float16* __restrict__ x0, const _Float16* __restrict__ x1,
                     const _Float16* __restrict__ w0, const _Float16* __restrict__ w1,
                     const float* __restrict__ bias,
                     float* __restrict__ dst, float* __restrict__ mst,
                     float* __restrict__ spst, int8_t* __restrict__ sout,
                     const float* __restrict__ tau_m, const float* __restrict__ tau_n) {
    __shared__ alignas(16) char SMEM[49152];
    // GEMM: A single buf 16 KB at 0 (A0 8K | A1 8K); B dbuf at 16K (per buf 16K: B0 8K | B1 8K)
    // epilogue alias: curS (f32 32x128 = 16 KB) at 0; sbuf (i8 128x32 = 4 KB) at 16K
    float*  curS = (float*)SMEM;
    int8_t* sbuf = (int8_t*)(SMEM + 16384);

    const int tid  = threadIdx.x;
    const int wave = tid >> 6, lane = tid & 63;
    const int bb = blockIdx.y;
    const int bm = bb * TP_, bn = blockIdx.x * 128;

    const int srow   = tid >> 2;
    const int chunk  = tid & 3;
    const int wchunk = chunk ^ ((srow >> 1) & 3);
    const size_t boff0 = (size_t)(bn + srow) * INP_ + wchunk * 8;   // pre-swizzled source
    const size_t boff1 = boff0 + (size_t)64 * INP_;
    const size_t aoff0 = (size_t)(bm + srow) * INP_ + chunk * 8;    // linear (swizzle on ds_write)
    const size_t aoff1 = aoff0 + (size_t)64 * INP_;

    const int wm = wave & 1, wn = wave >> 1;
    const int row = lane & 31;
    const int khq = lane >> 5;
    const int key = (lane >> 1) & 3;
    const int cK0 = ((0 + khq) ^ key) * 8;
    const int cK1 = ((2 + khq) ^ key) * 8;

    f32x16 acc[2][2] = {};
    int4 aR[4];

    auto stageB = [&](int kt, int base) {
        const int k0 = kt * 32;
        char* Sb = SMEM + 16384 + base;
        __builtin_amdgcn_global_load_lds((gptr_t)(w0 + boff0 + k0), (lptr_t)(Sb + wave * 1024),          16, 0, 0);
        __builtin_amdgcn_global_load_lds((gptr_t)(w0 + boff1 + k0), (lptr_t)(Sb + 4096  + wave * 1024),  16, 0, 0);
        __builtin_amdgcn_global_load_lds((gptr_t)(w1 + boff0 + k0), (lptr_t)(Sb + 8192  + wave * 1024),  16, 0, 0);
        __builtin_amdgcn_global_load_lds((gptr_t)(w1 + boff1 + k0), (lptr_t)(Sb + 12288 + wave * 1024),  16, 0, 0);
    };

    auto loadA = [&](int kt) {
        const int k0 = kt * 32;
        aR[0] = *(const int4*)(x0 + aoff0 + k0);
        aR[1] = *(const int4*)(x0 + aoff1 + k0);
        aR[2] = *(const int4*)(x1 + aoff0 + k0);
        aR[3] = *(const int4*)(x1 + aoff1 + k0);
    };

    auto writeA = [&]() {
        char* d = SMEM + srow * 64 + wchunk * 16;
        *(int4*)(d)         = aR[0];
        *(int4*)(d + 4096)  = aR[1];
        *(int4*)(d + 8192)  = aR[2];
        *(int4*)(d + 12288) = aR[3];
    };

    auto compute = [&](int bbase) {
        const _Float16* A0s = (const _Float16*)SMEM;
        const _Float16* A1s = (const _Float16*)(SMEM + 8192);
        const _Float16* B0b = (const _Float16*)(SMEM + 16384 + bbase);
        const _Float16* B1b = (const _Float16*)(SMEM + 16384 + bbase + 8192);
        half8 a0f[2][2], a1f[2][2], b0f[2][2], b1f[2][2];
#pragma unroll
        for (int mt = 0; mt < 2; mt++) {
            const _Float16* ar = &A0s[(wm * 64 + mt * 32 + row) * 32];
            a0f[mt][0] = *(const half8*)&ar[cK0];
            a0f[mt][1] = *(const half8*)&ar[cK1];
        }
#pragma unroll
        for (int nt = 0; nt < 2; nt++) {
            const _Float16* br = &B0b[(wn * 64 + nt * 32 + row) * 32];
            b0f[nt][0] = *(const half8*)&br[cK0];
            b0f[nt][1] = *(const half8*)&br[cK1];
        }
        __builtin_amdgcn_s_setprio(1);
#pragma unroll
        for (int ks = 0; ks < 2; ks++)
#pragma unroll
            for (int mt = 0; mt < 2; mt++)
#pragma unroll
                for (int nt = 0; nt < 2; nt++)
                    acc[mt][nt] = __builtin_amdgcn_mfma_f32_32x32x16_f16(
                        a0f[mt][ks], b0f[nt][ks], acc[mt][nt], 0, 0, 0);
        __builtin_amdgcn_s_setprio(0);
#pragma unroll
        for (int nt = 0; nt < 2; nt++) {
            const _Float16* br = &B1b[(wn * 64 + nt * 32 + row) * 32];
            b1f[nt][0] = *(const half8*)&br[cK0];
            b1f[nt][1] = *(const half8*)&br[cK1];
        }
        __builtin_amdgcn_s_setprio(1);
#pragma unroll
        for (int ks = 0; ks < 2; ks++)
#pragma unroll
            for (int mt = 0; mt < 2; mt++)
#pragma unroll
                for (int nt = 0; nt < 2; nt++)
                    acc[mt][nt] = __builtin_amdgcn_mfma_f32_32x32x16_f16(
                        a0f[mt][ks], b1f[nt][ks], acc[mt][nt], 0, 0, 0);
        __builtin_amdgcn_s_setprio(0);
#pragma unroll
        for (int mt = 0; mt < 2; mt++) {
            const _Float16* ar = &A1s[(wm * 64 + mt * 32 + row) * 32];
            a1f[mt][0] = *(const half8*)&ar[cK0];
            a1f[mt][1] = *(const half8*)&ar[cK1];
        }
        __builtin_amdgcn_s_setprio(1);
#pragma unroll
        for (int ks = 0; ks < 2; ks++)
#pragma unroll
            for (int mt = 0; mt < 2; mt++)
#pragma unroll
                for (int nt = 0; nt < 2; nt++)
                    acc[mt][nt] = __builtin_amdgcn_mfma_f32_32x32x16_f16(
                        a1f[mt][ks], b0f[nt][ks], acc[mt][nt], 0, 0, 0);
        __builtin_amdgcn_s_setprio(0);
    };

    // prologue: B(0) -> buf0; A(0) -> regs -> LDS
    stageB(0, 0);
    loadA(0);
    SB0();
    asm volatile("s_waitcnt vmcnt(0)" ::: "memory");
    writeA();
    asm volatile("s_waitcnt lgkmcnt(0)" ::: "memory");
    __builtin_amdgcn_s_barrier();

#pragma unroll 1
    for (int kt = 0; kt < INP_ / 32 - 1; kt++) {
        stageB(kt + 1, ((kt + 1) & 1) * 16384);
        loadA(kt + 1);
        SB0();
        compute((kt & 1) * 16384);
        __builtin_amdgcn_s_barrier();                       // all A-readers done
        asm volatile("s_waitcnt vmcnt(0)" ::: "memory");    // B(kt+1) staged, aR ready
        writeA();
        asm volatile("s_waitcnt lgkmcnt(0)" ::: "memory");
        __builtin_amdgcn_s_barrier();
    }
    compute(16384);   // kt = 21 (odd -> buf1)
    __syncthreads();  // GEMM fully done before LDS re-use

    // ---- epilogue: t-quarters of 32 rows; FULLY UNROLLED (compile-time acc indices) ----
    const int col = lane & 31;
    const int rb  = 4 * (lane >> 5);
    const int hg   = blockIdx.x * 32 + (tid & 31);
    const int sidx = bb * H_ + hg;
    float alpha = 0.f; float4 beta = {0.f, 0.f, 0.f, 0.f};
    float4 d = {0.f, 0.f, 0.f, 0.f};
    float m = 0.f, sp = 0.f;
    if (tid < 32) {
        alpha = 1.f / (1.f + expf(-tau_m[hg]));
        float4 tn = ((const float4*)tau_n)[hg];
        beta.x = 1.f / (1.f + expf(-tn.x));
        beta.y = 1.f / (1.f + expf(-tn.y));
        beta.z = 1.f / (1.f + expf(-tn.z));
        beta.w = 1.f / (1.f + expf(-tn.w));
        d  = ((const float4*)dst)[sidx];
        m  = mst[sidx];
        sp = spst[sidx];
    }
#pragma unroll
    for (int q = 0; q < 4; q++) {             // q compile-time -> acc[q&1] static (rule #20)
        if (wm == (q >> 1)) {
#pragma unroll
            for (int nt = 0; nt < 2; nt++) {
                const int lcol = wn * 64 + nt * 32 + col;
                const float bv = bias[bn + lcol];
#pragma unroll
                for (int reg = 0; reg < 16; reg++) {
                    const int trow = (reg & 3) + 8 * (reg >> 2) + rb;   // 0..31 in quarter
                    curS[trow * 128 + lcol] = acc[q & 1][nt][reg] + bv;
                }
            }
        }
        __syncthreads();
        if (tid < 32) {
            const int t1 = min(TC_, (q + 1) * 32);
            for (int t = q * 32; t < t1; t++) {
                float4 c = ((const float4*)(curS + (t - q * 32) * 128))[tid];
                d.x = beta.x * d.x + (1.f - beta.x) * c.x;
                d.y = beta.y * d.y + (1.f - beta.y) * c.y;
                d.z = beta.z * d.z + (1.f - beta.z) * c.z;
                d.w = beta.w * d.w + (1.f - beta.w) * c.w;
                float s4 = ((d.x + d.y) + d.z) + d.w;
                m = m * alpha + (1.f - alpha) * s4 - VTH_ * sp;
                sp = (m > VTH_) ? 1.f : 0.f;
                sbuf[t * 32 + tid] = (int8_t)(m > VTH_);
            }
        }
        __syncthreads();
    }
    if (tid < 32) {
        sbuf[125 * 32 + tid] = 0; sbuf[126 * 32 + tid] = 0; sbuf[127 * 32 + tid] = 0;
        ((float4*)dst)[sidx] = d;
        mst[sidx] = m;
        spst[sidx] = sp;
    }
    __syncthreads();
    if (tid < TP_) {   // 32 B of spikes per padded-t row
        int4* dp = (int4*)&sout[((size_t)(bm + tid)) * H_ + blockIdx.x * 32];
        const int4* s4 = (const int4*)&sbuf[tid * 32];
        dp[0] = s4[0]; dp[1] = s4[1];
    }
}

// ---------------- L2 fused: i8 GEMM (R4 loop, 32 KB dbuf) + t-quartered LIF scan ----------------
__global__ __launch_bounds__(256)
void l2_fused_kernel(const int8_t* __restrict__ A,
                     const int8_t* __restrict__ p2, const int8_t* __restrict__ p1,
                     const int8_t* __restrict__ p0,
                     const float* __restrict__ bias,
                     float* __restrict__ dst, float* __restrict__ mst,
                     float* __restrict__ spst, _Float16* __restrict__ sout,
                     const float* __restrict__ tau_m, const float* __restrict__ tau_n) {
    __shared__ alignas(16) char SMEM[32768];      // GEMM dbuf 2x16 KB | epi: curS 16 KB at 0, sbuf 8 KB at 16K
    int8_t*   S    = (int8_t*)SMEM;
    float*    curS = (float*)SMEM;
    _Float16* sbuf = (_Float16*)(SMEM + 16384);

    const int tid  = threadIdx.x;
    const int wave = tid >> 6, lane = tid & 63;
    const int bb = blockIdx.y;
    const int bm = bb * TP_, bn = blockIdx.x * 128;

    const int    srow  = tid >> 2;
    const int    skoff = (((tid & 3) ^ ((srow >> 1) & 3)) * 16);   // pre-swizzled source
    const size_t aoff0 = (size_t)(bm + srow) * H_ + skoff;
    const size_t aoff1 = aoff0 + (size_t)64 * H_;
    const size_t boff0 = (size_t)(bn + srow) * H_ + skoff;
    const size_t boff1 = boff0 + (size_t)64 * H_;
    const int lo = wave * 1024;

    const int wm = wave & 1, wn = wave >> 1;
    const int row = lane & 31;
    const int khq = lane >> 5;
    const int key = (lane >> 1) & 3;
    const int cK0 = ((0 + khq) ^ key) * 16;
    const int cK1 = ((2 + khq) ^ key) * 16;

    i32x16 acc[2][2] = {};

    auto stage = [&](int i, int base) {
        const int s  = i >> 3;
        const int k0 = (i & 7) * 64;
        const int8_t* pw = (s == 0) ? p2 : (s == 1) ? p1 : p0;
        int8_t* Sb = S + base;
        __builtin_amdgcn_global_load_lds((gptr_t)(A  + aoff0 + k0), (lptr_t)(Sb + lo),          16, 0, 0);
        __builtin_amdgcn_global_load_lds((gptr_t)(A  + aoff1 + k0), (lptr_t)(Sb + 4096  + lo),  16, 0, 0);
        __builtin_amdgcn_global_load_lds((gptr_t)(pw + boff0 + k0), (lptr_t)(Sb + 8192  + lo),  16, 0, 0);
        __builtin_amdgcn_global_load_lds((gptr_t)(pw + boff1 + k0), (lptr_t)(Sb + 12288 + lo),  16, 0, 0);
    };

    auto compute = [&](int base) {
        const int8_t* Ab = S + base;
        const int8_t* Bb = Ab + 8192;
        i32x4 af[2][2], bf[2][2];
#pragma unroll
        for (int mt = 0; mt < 2; mt++) {
            const int8_t* ar = &Ab[(wm * 64 + mt * 32 + row) * 64];
            af[mt][0] = *(const i32x4*)&ar[cK0];
            af[mt][1] = *(const i32x4*)&ar[cK1];
        }
#pragma unroll
        for (int nt = 0; nt < 2; nt++) {
            const int8_t* br = &Bb[(wn * 64 + nt * 32 + row) * 64];
            bf[nt][0] = *(const i32x4*)&br[cK0];
            bf[nt][1] = *(const i32x4*)&br[cK1];
        }
        __builtin_amdgcn_s_setprio(1);
#pragma unroll
        for (int ks = 0; ks < 2; ks++)
#pragma unroll
            for (int mt = 0; mt < 2; mt++)
#pragma unroll
                for (int nt = 0; nt < 2; nt++)
                    acc[mt][nt] = __builtin_amdgcn_mfma_i32_32x32x32_i8(
                        af[mt][ks], bf[nt][ks], acc[mt][nt], 0, 0, 0);
        __builtin_amdgcn_s_setprio(0);
    };

    stage(0, 0);
    asm volatile("s_waitcnt vmcnt(0)" ::: "memory");
    __builtin_amdgcn_s_barrier();

    int cur = 0;
#pragma unroll 1
    for (int i = 0; i < 23; i++) {
        const int base = cur * 16384;
        stage(i + 1, base ^ 16384);
        if (i == 8 || i == 16) {
#pragma unroll
            for (int mt = 0; mt < 2; mt++)
#pragma unroll
                for (int nt = 0; nt < 2; nt++) acc[mt][nt] *= 256;  // exact, |acc|<1.6e9
        }
        compute(base);
        asm volatile("s_waitcnt vmcnt(0) lgkmcnt(0)" ::: "memory");
        __builtin_amdgcn_s_barrier();
        cur ^= 1;
    }
    compute(cur * 16384);
    __syncthreads();

    // ---- epilogue: t-quarters, FULLY UNROLLED (compile-time acc indices), verbatim math ----
    const float scale = 1.f / 67108864.f;
    const int col = lane & 31;
    const int rb  = 4 * (lane >> 5);
    const int hg   = blockIdx.x * 32 + (tid & 31);
    const int sidx = bb * H_ + hg;
    float alpha = 0.f; float4 beta = {0.f, 0.f, 0.f, 0.f};
    float4 d = {0.f, 0.f, 0.f, 0.f};
    float m = 0.f, sp = 0.f;
    if (tid < 32) {
        alpha = 1.f / (1.f + expf(-tau_m[hg]));
        float4 tn = ((const float4*)tau_n)[hg];
        beta.x = 1.f / (1.f + expf(-tn.x));
        beta.y = 1.f / (1.f + expf(-tn.y));
        beta.z = 1.f / (1.f + expf(-tn.z));
        beta.w = 1.f / (1.f + expf(-tn.w));
        d  = ((const float4*)dst)[sidx];
        m  = mst[sidx];
        sp = spst[sidx];
    }
#pragma unroll
    for (int q = 0; q < 4; q++) {             // q compile-time -> acc[q&1] static (rule #20)
        if (wm == (q >> 1)) {
#pragma unroll
            for (int nt = 0; nt < 2; nt++) {
                const int lcol = wn * 64 + nt * 32 + col;
                const float bv = bias[bn + lcol];
#pragma unroll
                for (int reg = 0; reg < 16; reg++) {
                    const int trow = (reg & 3) + 8 * (reg >> 2) + rb;
                    curS[trow * 128 + lcol] = (float)acc[q & 1][nt][reg] * scale + bv;
                }
            }
        }
        __syncthreads();
        if (tid < 32) {
            const int t1 = min(TC_, (q + 1) * 32);
            for (int t = q * 32; t < t1; t++) {
                float4 c = ((const float4*)(curS + (t - q * 32) * 128))[tid];
                d.x = beta.x * d.x + (1.f - beta.x) * c.x;
                d.y = beta.y * d.y + (1.f - beta.y) * c.y;
                d.z = beta.z * d.z + (1.f - beta.z) * c.z;
                d.w = beta.w * d.w + (1.f - beta.w) * c.w;
                float s4 = ((d.x + d.y) + d.z) + d.w;
                m = m * alpha + (1.f - alpha) * s4 - VTH_ * sp;
                sp = (m > VTH_) ? 1.f : 0.f;
                sbuf[t * 32 + tid] = (_Float16)sp;
            }
        }
        __syncthreads();
    }
    if (tid < 32) {
        sbuf[125 * 32 + tid] = (_Float16)0.f;
        sbuf[126 * 32 + tid] = (_Float16)0.f;
        sbuf[127 * 32 + tid] = (_Float16)0.f;
        ((float4*)dst)[sidx] = d;
        mst[sidx] = m;
        spst[sidx] = sp;
    }
    __syncthreads();
    if (tid < TP_) {   // 64 B of f16 spikes per padded-t row
        int4* dp = (int4*)&sout[((size_t)(bm + tid)) * H_ + blockIdx.x * 32];
        const int4* s4 = (const int4*)&sbuf[tid * 32];
        dp[0] = s4[0]; dp[1] = s4[1]; dp[2] = s4[2]; dp[3] = s4[3];
    }
}

// ---------------- readout GEMM (MFMA 16x16): curo[b,t,o] = s2c . (wo0+wo1)^T + bo ----------------
// M = MP_ (t-padded); pad rows skipped at the store.
__global__ __launch_bounds__(256)
void rdot_mfma_kernel(const _Float16* __restrict__ s2c, const _Float16* __restrict__ wo0,
                      const _Float16* __restrict__ wo1, const float* __restrict__ bo,
                      float* __restrict__ curo, int t0) {
    __shared__ alignas(16) _Float16 S[2 * 6144];   // 24 KB: [buf][As 4096 | B0 1024 | B1 1024]
    const int tid  = threadIdx.x;
    const int wave = tid >> 6, lane = tid & 63;
    const int bm = blockIdx.x * 128;

    const int    srow  = tid >> 2;
    const int    skoff = (((tid & 3) ^ ((srow >> 1) & 3)) * 8);   // inverse-swizzled source
    const size_t aoff0 = (size_t)(bm + srow) * H_ + skoff;
    const size_t aoff1 = aoff0 + (size_t)64 * H_;
    const _Float16* bsrc = (wave < 2) ? wo0 : wo1;
    const int bw = wave & 1;
    const size_t boff = (size_t)(bw * 16 + (lane >> 2)) * H_
                      + ((lane & 3) ^ ((lane >> 3) & 3)) * 8;
    const int loA = wave * 512;
    const int loB = 4096 + (wave >> 1) * 1024 + bw * 512;

    const int fr = lane & 15;
    const int key = (lane >> 1) & 3;                 // = (fr>>1)&3
    const int cK  = (((lane >> 4) ^ key) * 8);       // swizzled k-column (halfs)

    f32x4 acc[2][2] = {};

    auto stage = [&](int kt, int base) {
        const int k0 = kt * 32;
        _Float16* Sb = S + base;
        __builtin_amdgcn_global_load_lds((gptr_t)(s2c + aoff0 + k0),  (lptr_t)(Sb + loA),        16, 0, 0);
        __builtin_amdgcn_global_load_lds((gptr_t)(s2c + aoff1 + k0),  (lptr_t)(Sb + 2048 + loA), 16, 0, 0);
        __builtin_amdgcn_global_load_lds((gptr_t)(bsrc + boff + k0),  (lptr_t)(Sb + loB),        16, 0, 0);
    };

    auto compute = [&](int base) {
        const _Float16* Ab  = S + base;
        const _Float16* B0b = Ab + 4096;
        const _Float16* B1b = Ab + 5120;
        half8 af[2], b0[2], b1[2];
#pragma unroll
        for (int mi = 0; mi < 2; mi++)
            af[mi] = *(const half8*)&Ab[(wave * 32 + mi * 16 + fr) * 32 + cK];
#pragma unroll
        for (int ni = 0; ni < 2; ni++) {
            b0[ni] = *(const half8*)&B0b[(ni * 16 + fr) * 32 + cK];
            b1[ni] = *(const half8*)&B1b[(ni * 16 + fr) * 32 + cK];
        }
        __builtin_amdgcn_s_setprio(1);
#pragma unroll
        for (int mi = 0; mi < 2; mi++)
#pragma unroll
            for (int ni = 0; ni < 2; ni++) {
                acc[mi][ni] = __builtin_amdgcn_mfma_f32_16x16x32_f16(af[mi], b0[ni], acc[mi][ni], 0, 0, 0);
                acc[mi][ni] = __builtin_amdgcn_mfma_f32_16x16x32_f16(af[mi], b1[ni], acc[mi][ni], 0, 0, 0);
            }
        __builtin_amdgcn_s_setprio(0);
    };

    stage(0, 0);
    asm volatile("s_waitcnt vmcnt(0)" ::: "memory");
    __builtin_amdgcn_s_barrier();

    int cur = 0;
    for (int kt = 0; kt < H_ / 32 - 1; kt++) {
        const int base = cur * 6144;
        stage(kt + 1, base ^ 6144);
        compute(base);
        asm volatile("s_waitcnt vmcnt(0) lgkmcnt(0)" ::: "memory");
        __builtin_amdgcn_s_barrier();
        cur ^= 1;
    }
    compute(cur * 6144);

    const int cc = lane & 15;
    const int cr = (lane >> 4) * 4;
#pragma unroll
    for (int ni = 0; ni < 2; ni++) {
        const int gc = ni * 16 + cc;
        if (gc < OUT_) {
            const float bv = bo[gc];
#pragma unroll
            for (int mi = 0; mi < 2; mi++) {
#pragma unroll
                for (int r = 0; r < 4; r++) {
                    const int gr = bm + wave * 32 + mi * 16 + cr + r;
                    const int bb = gr >> 7, tl = gr & (TP_ - 1);
                    if (tl < TC_)
                        curo[((size_t)bb * T_ + t0 + tl) * OUT_ + gc] = acc[mi][ni][r] + bv;
                }
            }
        }
    }
}

// ---------------- parallel readout: segmented scan + t-parallel softmax-sum ----------------
#define RT_SEG 12
#define RT_LEN 21   // 12*21 = 252 >= 250

__global__ __launch_bounds__(256)
void readout_kernel(const float* __restrict__ curo, const float* __restrict__ tau_mo,
                    float* __restrict__ out) {
    __shared__ float moS[T_ * OUT_];          // 20 KB
    __shared__ float segA[RT_SEG][OUT_];
    __shared__ float segU[RT_SEG][OUT_];
    __shared__ float pre[RT_SEG][OUT_];
    __shared__ float accS[OUT_];
    const int b = blockIdx.x;
    const int tid = threadIdx.x;
    const float* cb = curo + (size_t)b * T_ * OUT_;

    const int o = tid % OUT_;
    const int sg = tid / OUT_;
    const float ao = 1.f / (1.f + expf(-tau_mo[o]));

    if (tid < RT_SEG * OUT_) {
        int t0 = sg * RT_LEN;
        int t1 = min(T_, t0 + RT_LEN);
        float u = 0.f, Ap = 1.f;
        for (int t = t0; t < t1; t++) {
            u = ao * u + (1.f - ao) * cb[t * OUT_ + o];
            Ap *= ao;
        }
        segU[sg][o] = u; segA[sg][o] = Ap;
    }
    if (tid < OUT_) accS[tid] = 0.f;
    __syncthreads();
    if (tid < OUT_) {
        float m = 0.f;
        for (int s = 0; s < RT_SEG; s++) {
            pre[s][tid] = m;
            m = segA[s][tid] * m + segU[s][tid];
        }
    }
    __syncthreads();
    if (tid < RT_SEG * OUT_) {
        int t0 = sg * RT_LEN;
        int t1 = min(T_, t0 + RT_LEN);
        float m = pre[sg][o];
        for (int t = t0; t < t1; t++) {
            m = ao * m + (1.f - ao) * cb[t * OUT_ + o];
            moS[t * OUT_ + o] = m;
        }
    }
    __syncthreads();
    if (tid >= WARM_ + 1 && tid < T_) {
        int t = tid;
        float mx = -3.0e38f;
#pragma unroll
        for (int o2 = 0; o2 < OUT_; o2++) mx = fmaxf(mx, moS[t * OUT_ + o2]);
        float es[OUT_]; float se = 0.f;
#pragma unroll
        for (int o2 = 0; o2 < OUT_; o2++) {
            float e = expf(moS[t * OUT_ + o2] - mx);
            es[o2] = e; se += e;
        }
        float inv = 1.f / se;
#pragma unroll
        for (int o2 = 0; o2 < OUT_; o2++) atomicAdd(&accS[o2], es[o2] * inv);
    }
    __syncthreads();
    if (tid < OUT_) out[(size_t)b * OUT_ + tid] = accS[tid];
}

extern "C" void kernel_launch(void* const* d_in, const int* in_sizes, int n_in,
                              void* d_out, int out_size, void* d_ws, size_t ws_size,
                              hipStream_t stream) {
    const float* x      = (const float*)d_in[0];
    const float* W1     = (const float*)d_in[1];
    const float* b1     = (const float*)d_in[2];
    const float* tau_m1 = (const float*)d_in[3];
    const float* tau_n1 = (const float*)d_in[4];
    const float* mask1  = (const float*)d_in[5];
    const float* W2     = (const float*)d_in[6];
    const float* b2     = (const float*)d_in[7];
    const float* tau_m2 = (const float*)d_in[8];
    const float* tau_n2 = (const float*)d_in[9];
    const float* mask2  = (const float*)d_in[10];
    const float* Wo     = (const float*)d_in[11];
    const float* bo     = (const float*)d_in[12];
    const float* tau_mo = (const float*)d_in[13];
    float* out = (float*)d_out;

    // Fused-scan design: 2 chunks of 125 timesteps (padded to 128). ~86 MB.
    char* p = (char*)d_ws;
    auto alloc = [&](size_t bytes) { char* r = p; p += (bytes + 255) & ~(size_t)255; return r; };
    _Float16* w10 = (_Float16*)alloc((size_t)HB_ * INP_ * 2);
    _Float16* w11 = (_Float16*)alloc((size_t)HB_ * INP_ * 2);
    int8_t*   q2  = (int8_t*)alloc((size_t)HB_ * H_);
    int8_t*   q1  = (int8_t*)alloc((size_t)HB_ * H_);
    int8_t*   q0  = (int8_t*)alloc((size_t)HB_ * H_);
    _Float16* wo0 = (_Float16*)alloc((size_t)32 * H_ * 2);
    _Float16* wo1 = (_Float16*)alloc((size_t)32 * H_ * 2);
    _Float16* xc0 = (_Float16*)alloc((size_t)MP_ * INP_ * 2);
    _Float16* xc1 = (_Float16*)alloc((size_t)MP_ * INP_ * 2);
    int8_t*   s1c = (int8_t*)alloc((size_t)MP_ * H_);
    _Float16* s2c = (_Float16*)alloc((size_t)MP_ * H_ * 2);
    float* curo   = (float*)alloc((size_t)B_ * T_ * OUT_ * 4);
    float* st     = (float*)alloc((size_t)786432 * 4);
    float* d1  = st;
    float* m1  = d1 + (size_t)B_ * H_ * BR_;
    float* sp1 = m1 + (size_t)B_ * H_;
    float* d2  = sp1 + (size_t)B_ * H_;
    float* m2  = d2 + (size_t)B_ * H_ * BR_;
    float* sp2 = m2 + (size_t)B_ * H_;

    w1prep_kernel<<<(HB_ * INP_ + 255) / 256, 256, 0, stream>>>(W1, mask1, w10, w11);
    w2prep_kernel<<<(HB_ * H_ + 255) / 256, 256, 0, stream>>>(W2, mask2, q2, q1, q0);
    woprep_kernel<<<(32 * H_ + 255) / 256, 256, 0, stream>>>(Wo, wo0, wo1);
    zero_kernel<<<(786432 / 4 + 255) / 256, 256, 0, stream>>>(st, 786432 / 4);

    dim3 gg(HB_ / 128, B_);                 // (16 n-tiles, 128 batches)
    for (int c = 0; c < 2; c++) {
        const int t0 = c * TC_;
        convx_kernel<<<(MP_ * INP_) / 256, 256, 0, stream>>>(x, xc0, xc1, t0);
        l1_fused_kernel<<<gg, 256, 0, stream>>>(xc0, xc1, w10, w11, b1,
                                                d1, m1, sp1, s1c, tau_m1, tau_n1);
        l2_fused_kernel<<<gg, 256, 0, stream>>>(s1c, q2, q1, q0, b2,
                                                d2, m2, sp2, s2c, tau_m2, tau_n2);
        rdot_mfma_kernel<<<MP_ / 128, 256, 0, stream>>>(s2c, wo0, wo1, bo, curo, t0);
    }
    readout_kernel<<<B_, 256, 0, stream>>>(curo, tau_mo, out);
}

// Round 8
// 781.839 us; speedup vs baseline: 1.6427x; 1.3171x over previous
//
#include <hip/hip_runtime.h>
#include <math.h>
#include <stdint.h>

// Problem dims
#define B_    128
#define T_    250
#define IN_   700
#define INP_  704    // padded to 32 (22 k-tiles of 32)
#define H_    512
#define OUT_  20
#define BR_   4
#define HB_   2048   // H_*BR_
#define WARM_ 10
#define VTH_  1.0f
#define TC_   125    // timesteps per chunk (2 chunks x 125)
#define TP_   128    // padded timesteps per chunk (one m-block = one batch)
#define MP_   16384  // B_ * TP_  (padded GEMM M per chunk)

typedef __attribute__((ext_vector_type(8)))  _Float16 half8;
typedef __attribute__((ext_vector_type(4)))  float f32x4;
typedef __attribute__((ext_vector_type(16))) float f32x16;
typedef __attribute__((ext_vector_type(4)))  int i32x4;
typedef __attribute__((ext_vector_type(16))) int i32x16;
typedef const __attribute__((address_space(1))) void* gptr_t;
typedef __attribute__((address_space(3))) void* lptr_t;

// ---------------- prep: split fp32 -> hi/lo fp16 planes (layer 1) ----------------
__global__ __launch_bounds__(256)
void w1prep_kernel(const float* __restrict__ W, const float* __restrict__ M,
                   _Float16* __restrict__ w0, _Float16* __restrict__ w1) {
    int i = blockIdx.x * 256 + threadIdx.x;           // over HB_*INP_
    if (i >= HB_ * INP_) return;
    int r = i / INP_, c = i - r * INP_;
    float v = (c < IN_) ? W[(size_t)r * IN_ + c] * M[(size_t)r * IN_ + c] : 0.f;
    _Float16 h0 = (_Float16)v;
    w0[i] = h0;
    w1[i] = (_Float16)(v - (float)h0);
}

// ---------------- prep: layer-2 weights -> 3 signed radix-256 i8 planes, scale 2^26 ----------------
__global__ __launch_bounds__(256)
void w2prep_kernel(const float* __restrict__ W, const float* __restrict__ M,
                   int8_t* __restrict__ p2, int8_t* __restrict__ p1,
                   int8_t* __restrict__ p0) {
    int i = blockIdx.x * 256 + threadIdx.x;           // over HB_*H_
    if (i >= HB_ * H_) return;
    float v = W[i] * M[i];
    int q = (int)lrintf(v * 67108864.f);              // |q| <= ~2.97e6
    int b0 = (int)(int8_t)(q & 0xFF);  q = (q - b0) >> 8;
    int b1 = (int)(int8_t)(q & 0xFF);  int b2 = (q - b1) >> 8;   // |b2| <= 46
    p0[i] = (int8_t)b0; p1[i] = (int8_t)b1; p2[i] = (int8_t)b2;
}

// ---------------- prep: readout weights -> hi/lo fp16 planes, n padded to 32 ----------------
__global__ __launch_bounds__(256)
void woprep_kernel(const float* __restrict__ Wo, _Float16* __restrict__ wo0,
                   _Float16* __restrict__ wo1) {
    int i = blockIdx.x * 256 + threadIdx.x;           // over 32*H_
    if (i >= 32 * H_) return;
    int n = i >> 9;
    float v = (n < OUT_) ? Wo[(size_t)n * H_ + (i & (H_ - 1))] : 0.f;
    _Float16 h0 = (_Float16)v;
    wo0[i] = h0;
    wo1[i] = (_Float16)(v - (float)h0);
}

// per-chunk x conversion -> t-padded rows: row r = bb*TP_ + tl, tl in [0,TP_);
// rows with tl >= TC_ (and cols >= IN_) are zero.
__global__ __launch_bounds__(256)
void convx_kernel(const float* __restrict__ x, _Float16* __restrict__ x0,
                  _Float16* __restrict__ x1, int t0) {
    int i = blockIdx.x * 256 + threadIdx.x;
    if (i >= MP_ * INP_) return;
    int r = i / INP_, c = i - r * INP_;
    int bb = r >> 7, tl = r & (TP_ - 1);
    float v = (tl < TC_ && c < IN_) ? x[((size_t)bb * T_ + t0 + tl) * IN_ + c] : 0.f;
    _Float16 h0 = (_Float16)v;
    x0[i] = h0;
    x1[i] = (_Float16)(v - (float)h0);
}

__global__ void zero_kernel(float* __restrict__ p, int n4) {
    int i = blockIdx.x * blockDim.x + threadIdx.x;
    if (i < n4) ((float4*)p)[i] = make_float4(0.f, 0.f, 0.f, 0.f);
}

// ---------------- L1 fused: GEMM (32x32x16 f16 MFMA, 3 products) + LIF scan epilogue ----
// One m-block = one batch element (rows = bb*128 + t, t=0..127 padded). After the
// K-loop the full [128 t x 128 hb] current tile is staged to LDS (acc + bias,
// verbatim old C-write expression) and wave-0 lanes<32 run the old SCAN_BODY
// float4 math over t (exact order), producing spikes + carry states. The 131 MB
// fp32 `cur` HBM round-trip is eliminated.  [R4-proven: 179 us, VGPR 88, no spill]
__global__ __launch_bounds__(256)
void l1_fused_kernel(const _Float16* __restrict__ x0, const _Float16* __restrict__ x1,
                     const _Float16* __restrict__ w0, const _Float16* __restrict__ w1,
                     const float* __restrict__ bias,
                     float* __restrict__ dst, float* __restrict__ mst,
                     float* __restrict__ spst, int8_t* __restrict__ sout,
                     const float* __restrict__ tau_m, const float* __restrict__ tau_n) {
    __shared__ alignas(16) char SMEM[69632];      // GEMM dbuf 64 KB | epilogue: curS 64 KB (aliased) + sbuf 4 KB
    _Float16* S    = (_Float16*)SMEM;             // 2 x 16384 halfs
    float*    curS = (float*)SMEM;                // 128 x 128 f32
    int8_t*   sbuf = (int8_t*)(SMEM + 65536);     // 128 x 32 spikes

    const int tid  = threadIdx.x;
    const int wave = tid >> 6, lane = tid & 63;
    const int bb = blockIdx.y;
    const int bm = bb * TP_, bn = blockIdx.x * 128;

    const int    srow  = tid >> 2;
    const int    skoff = (((tid & 3) ^ ((srow >> 1) & 3)) * 8);   // inverse-swizzled source
    const size_t aoff0 = (size_t)(bm + srow) * INP_ + skoff;
    const size_t aoff1 = aoff0 + (size_t)64 * INP_;
    const size_t boff0 = (size_t)(bn + srow) * INP_ + skoff;
    const size_t boff1 = boff0 + (size_t)64 * INP_;
    const int lo = wave * 512;

    const int wm = wave & 1, wn = wave >> 1;
    const int row = lane & 31;
    const int khq = lane >> 5;
    const int key = (lane >> 1) & 3;
    const int cK0 = ((0 + khq) ^ key) * 8;
    const int cK1 = ((2 + khq) ^ key) * 8;

    f32x16 acc[2][2] = {};

    auto stage = [&](int kt, int base) {
        const int k0 = kt * 32;
        _Float16* Sb = S + base;
        __builtin_amdgcn_global_load_lds((gptr_t)(x0 + aoff0 + k0), (lptr_t)(Sb + lo),          16, 0, 0);
        __builtin_amdgcn_global_load_lds((gptr_t)(x0 + aoff1 + k0), (lptr_t)(Sb + 2048  + lo),  16, 0, 0);
        __builtin_amdgcn_global_load_lds((gptr_t)(x1 + aoff0 + k0), (lptr_t)(Sb + 4096  + lo),  16, 0, 0);
        __builtin_amdgcn_global_load_lds((gptr_t)(x1 + aoff1 + k0), (lptr_t)(Sb + 6144  + lo),  16, 0, 0);
        __builtin_amdgcn_global_load_lds((gptr_t)(w0 + boff0 + k0), (lptr_t)(Sb + 8192  + lo),  16, 0, 0);
        __builtin_amdgcn_global_load_lds((gptr_t)(w0 + boff1 + k0), (lptr_t)(Sb + 10240 + lo),  16, 0, 0);
        __builtin_amdgcn_global_load_lds((gptr_t)(w1 + boff0 + k0), (lptr_t)(Sb + 12288 + lo),  16, 0, 0);
        __builtin_amdgcn_global_load_lds((gptr_t)(w1 + boff1 + k0), (lptr_t)(Sb + 14336 + lo),  16, 0, 0);
    };

    auto compute = [&](int base) {
        const _Float16* A0b = S + base;
        const _Float16* A1b = A0b + 4096;
        const _Float16* B0b = A0b + 8192;
        const _Float16* B1b = A0b + 12288;
        half8 a0f[2][2], a1f[2][2], b0f[2][2], b1f[2][2];
#pragma unroll
        for (int mt = 0; mt < 2; mt++) {
            const _Float16* ar = &A0b[(wm * 64 + mt * 32 + row) * 32];
            a0f[mt][0] = *(const half8*)&ar[cK0];
            a0f[mt][1] = *(const half8*)&ar[cK1];
        }
#pragma unroll
        for (int nt = 0; nt < 2; nt++) {
            const _Float16* br = &B0b[(wn * 64 + nt * 32 + row) * 32];
            b0f[nt][0] = *(const half8*)&br[cK0];
            b0f[nt][1] = *(const half8*)&br[cK1];
        }
        __builtin_amdgcn_s_setprio(1);
#pragma unroll
        for (int ks = 0; ks < 2; ks++)
#pragma unroll
            for (int mt = 0; mt < 2; mt++)
#pragma unroll
                for (int nt = 0; nt < 2; nt++)
                    acc[mt][nt] = __builtin_amdgcn_mfma_f32_32x32x16_f16(
                        a0f[mt][ks], b0f[nt][ks], acc[mt][nt], 0, 0, 0);
        __builtin_amdgcn_s_setprio(0);
#pragma unroll
        for (int nt = 0; nt < 2; nt++) {
            const _Float16* br = &B1b[(wn * 64 + nt * 32 + row) * 32];
            b1f[nt][0] = *(const half8*)&br[cK0];
            b1f[nt][1] = *(const half8*)&br[cK1];
        }
        __builtin_amdgcn_s_setprio(1);
#pragma unroll
        for (int ks = 0; ks < 2; ks++)
#pragma unroll
            for (int mt = 0; mt < 2; mt++)
#pragma unroll
                for (int nt = 0; nt < 2; nt++)
                    acc[mt][nt] = __builtin_amdgcn_mfma_f32_32x32x16_f16(
                        a0f[mt][ks], b1f[nt][ks], acc[mt][nt], 0, 0, 0);
        __builtin_amdgcn_s_setprio(0);
#pragma unroll
        for (int mt = 0; mt < 2; mt++) {
            const _Float16* ar = &A1b[(wm * 64 + mt * 32 + row) * 32];
            a1f[mt][0] = *(const half8*)&ar[cK0];
            a1f[mt][1] = *(const half8*)&ar[cK1];
        }
        __builtin_amdgcn_s_setprio(1);
#pragma unroll
        for (int ks = 0; ks < 2; ks++)
#pragma unroll
            for (int mt = 0; mt < 2; mt++)
#pragma unroll
                for (int nt = 0; nt < 2; nt++)
                    acc[mt][nt] = __builtin_amdgcn_mfma_f32_32x32x16_f16(
                        a1f[mt][ks], b0f[nt][ks], acc[mt][nt], 0, 0, 0);
        __builtin_amdgcn_s_setprio(0);
    };

    stage(0, 0);
    asm volatile("s_waitcnt vmcnt(0)" ::: "memory");
    __builtin_amdgcn_s_barrier();

    int cur = 0;
    for (int kt = 0; kt < INP_ / 32 - 1; kt++) {
        const int base = cur * 16384;
        stage(kt + 1, base ^ 16384);
        compute(base);
        asm volatile("s_waitcnt vmcnt(0) lgkmcnt(0)" ::: "memory");
        __builtin_amdgcn_s_barrier();
        cur ^= 1;
    }
    compute(cur * 16384);
    __syncthreads();   // all waves done reading S before curS overwrite

    // ---- epilogue: stage currents (acc + bias) to LDS ----
    const int col = lane & 31;
    const int rb  = 4 * (lane >> 5);
#pragma unroll
    for (int nt = 0; nt < 2; nt++) {
        const int lcol = wn * 64 + nt * 32 + col;
        const float bv = bias[bn + lcol];
#pragma unroll
        for (int mt = 0; mt < 2; mt++) {
#pragma unroll
            for (int reg = 0; reg < 16; reg++) {
                const int trow = wm * 64 + mt * 32 + (reg & 3) + 8 * (reg >> 2) + rb;
                curS[trow * 128 + lcol] = acc[mt][nt][reg] + bv;
            }
        }
    }
    __syncthreads();

    // ---- LIF scan over t (verbatim old SCAN_BODY math, LDS-sourced) ----
    if (tid < 32) {
        const int hg   = blockIdx.x * 32 + tid;       // global h neuron
        const int sidx = bb * H_ + hg;
        float alpha = 1.f / (1.f + expf(-tau_m[hg]));
        float4 tn = ((const float4*)tau_n)[hg];
        float4 beta;
        beta.x = 1.f / (1.f + expf(-tn.x));
        beta.y = 1.f / (1.f + expf(-tn.y));
        beta.z = 1.f / (1.f + expf(-tn.z));
        beta.w = 1.f / (1.f + expf(-tn.w));
        float4 d = ((const float4*)dst)[sidx];
        float m = mst[sidx];
        float sp = spst[sidx];
#pragma unroll 5
        for (int t = 0; t < TC_; t++) {
            float4 c = ((const float4*)(curS + t * 128))[tid];
            d.x = beta.x * d.x + (1.f - beta.x) * c.x;
            d.y = beta.y * d.y + (1.f - beta.y) * c.y;
            d.z = beta.z * d.z + (1.f - beta.z) * c.z;
            d.w = beta.w * d.w + (1.f - beta.w) * c.w;
            float s4 = ((d.x + d.y) + d.z) + d.w;
            m = m * alpha + (1.f - alpha) * s4 - VTH_ * sp;
            sp = (m > VTH_) ? 1.f : 0.f;
            sbuf[t * 32 + tid] = (int8_t)(m > VTH_);
        }
        sbuf[125 * 32 + tid] = 0; sbuf[126 * 32 + tid] = 0; sbuf[127 * 32 + tid] = 0;
        ((float4*)dst)[sidx] = d;
        mst[sidx] = m;
        spst[sidx] = sp;
    }
    __syncthreads();
    if (tid < TP_) {   // coalesced spike write: 32 B per padded-t row
        int4* dp = (int4*)&sout[((size_t)(bm + tid)) * H_ + blockIdx.x * 32];
        const int4* sp4 = (const int4*)&sbuf[tid * 32];
        dp[0] = sp4[0]; dp[1] = sp4[1];
    }
}

// ---------------- L2 fused: i8 fixed-point GEMM (32x32x32, Horner over 3 planes) + LIF scan ----
__global__ __launch_bounds__(256)
void l2_fused_kernel(const int8_t* __restrict__ A,
                     const int8_t* __restrict__ p2, const int8_t* __restrict__ p1,
                     const int8_t* __restrict__ p0,
                     const float* __restrict__ bias,
                     float* __restrict__ dst, float* __restrict__ mst,
                     float* __restrict__ spst, _Float16* __restrict__ sout,
                     const float* __restrict__ tau_m, const float* __restrict__ tau_n) {
    __shared__ alignas(16) char SMEM[73728];      // GEMM dbuf 32 KB | curS 64 KB (aliased) + sbuf 8 KB
    int8_t*   S    = (int8_t*)SMEM;               // 2 x 16384 i8
    float*    curS = (float*)SMEM;                // 128 x 128 f32
    _Float16* sbuf = (_Float16*)(SMEM + 65536);   // 128 x 32 f16 spikes

    const int tid  = threadIdx.x;
    const int wave = tid >> 6, lane = tid & 63;
    const int bb = blockIdx.y;
    const int bm = bb * TP_, bn = blockIdx.x * 128;

    const int    srow  = tid >> 2;
    const int    skoff = (((tid & 3) ^ ((srow >> 1) & 3)) * 16);   // inverse-swizzled source
    const size_t aoff0 = (size_t)(bm + srow) * H_ + skoff;
    const size_t aoff1 = aoff0 + (size_t)64 * H_;
    const size_t boff0 = (size_t)(bn + srow) * H_ + skoff;
    const size_t boff1 = boff0 + (size_t)64 * H_;
    const int lo = wave * 1024;

    const int wm = wave & 1, wn = wave >> 1;
    const int row = lane & 31;
    const int khq = lane >> 5;
    const int key = (lane >> 1) & 3;
    const int cK0 = ((0 + khq) ^ key) * 16;
    const int cK1 = ((2 + khq) ^ key) * 16;

    i32x16 acc[2][2] = {};

    auto stage = [&](int i, int base) {
        const int s  = i >> 3;
        const int k0 = (i & 7) * 64;
        const int8_t* pw = (s == 0) ? p2 : (s == 1) ? p1 : p0;
        int8_t* Sb = S + base;
        __builtin_amdgcn_global_load_lds((gptr_t)(A  + aoff0 + k0), (lptr_t)(Sb + lo),          16, 0, 0);
        __builtin_amdgcn_global_load_lds((gptr_t)(A  + aoff1 + k0), (lptr_t)(Sb + 4096  + lo),  16, 0, 0);
        __builtin_amdgcn_global_load_lds((gptr_t)(pw + boff0 + k0), (lptr_t)(Sb + 8192  + lo),  16, 0, 0);
        __builtin_amdgcn_global_load_lds((gptr_t)(pw + boff1 + k0), (lptr_t)(Sb + 12288 + lo),  16, 0, 0);
    };

    auto compute = [&](int base) {
        const int8_t* Ab = S + base;
        const int8_t* Bb = Ab + 8192;
        i32x4 af[2][2], bf[2][2];
#pragma unroll
        for (int mt = 0; mt < 2; mt++) {
            const int8_t* ar = &Ab[(wm * 64 + mt * 32 + row) * 64];
            af[mt][0] = *(const i32x4*)&ar[cK0];
            af[mt][1] = *(const i32x4*)&ar[cK1];
        }
#pragma unroll
        for (int nt = 0; nt < 2; nt++) {
            const int8_t* br = &Bb[(wn * 64 + nt * 32 + row) * 64];
            bf[nt][0] = *(const i32x4*)&br[cK0];
            bf[nt][1] = *(const i32x4*)&br[cK1];
        }
        __builtin_amdgcn_s_setprio(1);
#pragma unroll
        for (int ks = 0; ks < 2; ks++)
#pragma unroll
            for (int mt = 0; mt < 2; mt++)
#pragma unroll
                for (int nt = 0; nt < 2; nt++)
                    acc[mt][nt] = __builtin_amdgcn_mfma_i32_32x32x32_i8(
                        af[mt][ks], bf[nt][ks], acc[mt][nt], 0, 0, 0);
        __builtin_amdgcn_s_setprio(0);
    };

    stage(0, 0);
    asm volatile("s_waitcnt vmcnt(0)" ::: "memory");
    __builtin_amdgcn_s_barrier();

    int cur = 0;
    for (int i = 0; i < 23; i++) {
        const int base = cur * 16384;
        stage(i + 1, base ^ 16384);
        if (i == 8 || i == 16) {
#pragma unroll
            for (int mt = 0; mt < 2; mt++)
#pragma unroll
                for (int nt = 0; nt < 2; nt++) acc[mt][nt] *= 256;  // exact, |acc|<1.6e9
        }
        compute(base);
        asm volatile("s_waitcnt vmcnt(0) lgkmcnt(0)" ::: "memory");
        __builtin_amdgcn_s_barrier();
        cur ^= 1;
    }
    compute(cur * 16384);
    __syncthreads();

    // ---- epilogue: stage currents to LDS (verbatim old C-write expression) ----
    const float scale = 1.f / 67108864.f;
    const int col = lane & 31;
    const int rb  = 4 * (lane >> 5);
#pragma unroll
    for (int nt = 0; nt < 2; nt++) {
        const int lcol = wn * 64 + nt * 32 + col;
        const float bv = bias[bn + lcol];
#pragma unroll
        for (int mt = 0; mt < 2; mt++) {
#pragma unroll
            for (int reg = 0; reg < 16; reg++) {
                const int trow = wm * 64 + mt * 32 + (reg & 3) + 8 * (reg >> 2) + rb;
                curS[trow * 128 + lcol] = (float)acc[mt][nt][reg] * scale + bv;
            }
        }
    }
    __syncthreads();

    if (tid < 32) {
        const int hg   = blockIdx.x * 32 + tid;
        const int sidx = bb * H_ + hg;
        float alpha = 1.f / (1.f + expf(-tau_m[hg]));
        float4 tn = ((const float4*)tau_n)[hg];
        float4 beta;
        beta.x = 1.f / (1.f + expf(-tn.x));
        beta.y = 1.f / (1.f + expf(-tn.y));
        beta.z = 1.f / (1.f + expf(-tn.z));
        beta.w = 1.f / (1.f + expf(-tn.w));
        float4 d = ((const float4*)dst)[sidx];
        float m = mst[sidx];
        float sp = spst[sidx];
#pragma unroll 5
        for (int t = 0; t < TC_; t++) {
            float4 c = ((const float4*)(curS + t * 128))[tid];
            d.x = beta.x * d.x + (1.f - beta.x) * c.x;
            d.y = beta.y * d.y + (1.f - beta.y) * c.y;
            d.z = beta.z * d.z + (1.f - beta.z) * c.z;
            d.w = beta.w * d.w + (1.f - beta.w) * c.w;
            float s4 = ((d.x + d.y) + d.z) + d.w;
            m = m * alpha + (1.f - alpha) * s4 - VTH_ * sp;
            sp = (m > VTH_) ? 1.f : 0.f;
            sbuf[t * 32 + tid] = (_Float16)sp;
        }
        sbuf[125 * 32 + tid] = (_Float16)0.f;
        sbuf[126 * 32 + tid] = (_Float16)0.f;
        sbuf[127 * 32 + tid] = (_Float16)0.f;
        ((float4*)dst)[sidx] = d;
        mst[sidx] = m;
        spst[sidx] = sp;
    }
    __syncthreads();
    if (tid < TP_) {   // 64 B per padded-t row
        int4* dp = (int4*)&sout[((size_t)(bm + tid)) * H_ + blockIdx.x * 32];
        const int4* sp4 = (const int4*)&sbuf[tid * 32];
        dp[0] = sp4[0]; dp[1] = sp4[1]; dp[2] = sp4[2]; dp[3] = sp4[3];
    }
}

// ---------------- readout GEMM (MFMA 16x16): curo[b,t,o] = s2c . (wo0+wo1)^T + bo ----------------
// M = MP_ (t-padded); pad rows skipped at the store.
__global__ __launch_bounds__(256)
void rdot_mfma_kernel(const _Float16* __restrict__ s2c, const _Float16* __restrict__ wo0,
                      const _Float16* __restrict__ wo1, const float* __restrict__ bo,
                      float* __restrict__ curo, int t0) {
    __shared__ alignas(16) _Float16 S[2 * 6144];   // 24 KB: [buf][As 4096 | B0 1024 | B1 1024]
    const int tid  = threadIdx.x;
    const int wave = tid >> 6, lane = tid & 63;
    const int bm = blockIdx.x * 128;

    const int    srow  = tid >> 2;
    const int    skoff = (((tid & 3) ^ ((srow >> 1) & 3)) * 8);   // inverse-swizzled source
    const size_t aoff0 = (size_t)(bm + srow) * H_ + skoff;
    const size_t aoff1 = aoff0 + (size_t)64 * H_;
    const _Float16* bsrc = (wave < 2) ? wo0 : wo1;
    const int bw = wave & 1;
    const size_t boff = (size_t)(bw * 16 + (lane >> 2)) * H_
                      + ((lane & 3) ^ ((lane >> 3) & 3)) * 8;
    const int loA = wave * 512;
    const int loB = 4096 + (wave >> 1) * 1024 + bw * 512;

    const int fr = lane & 15;
    const int key = (lane >> 1) & 3;                 // = (fr>>1)&3
    const int cK  = (((lane >> 4) ^ key) * 8);       // swizzled k-column (halfs)

    f32x4 acc[2][2] = {};

    auto stage = [&](int kt, int base) {
        const int k0 = kt * 32;
        _Float16* Sb = S + base;
        __builtin_amdgcn_global_load_lds((gptr_t)(s2c + aoff0 + k0),  (lptr_t)(Sb + loA),        16, 0, 0);
        __builtin_amdgcn_global_load_lds((gptr_t)(s2c + aoff1 + k0),  (lptr_t)(Sb + 2048 + loA), 16, 0, 0);
        __builtin_amdgcn_global_load_lds((gptr_t)(bsrc + boff + k0),  (lptr_t)(Sb + loB),        16, 0, 0);
    };

    auto compute = [&](int base) {
        const _Float16* Ab  = S + base;
        const _Float16* B0b = Ab + 4096;
        const _Float16* B1b = Ab + 5120;
        half8 af[2], b0[2], b1[2];
#pragma unroll
        for (int mi = 0; mi < 2; mi++)
            af[mi] = *(const half8*)&Ab[(wave * 32 + mi * 16 + fr) * 32 + cK];
#pragma unroll
        for (int ni = 0; ni < 2; ni++) {
            b0[ni] = *(const half8*)&B0b[(ni * 16 + fr) * 32 + cK];
            b1[ni] = *(const half8*)&B1b[(ni * 16 + fr) * 32 + cK];
        }
        __builtin_amdgcn_s_setprio(1);
#pragma unroll
        for (int mi = 0; mi < 2; mi++)
#pragma unroll
            for (int ni = 0; ni < 2; ni++) {
                acc[mi][ni] = __builtin_amdgcn_mfma_f32_16x16x32_f16(af[mi], b0[ni], acc[mi][ni], 0, 0, 0);
                acc[mi][ni] = __builtin_amdgcn_mfma_f32_16x16x32_f16(af[mi], b1[ni], acc[mi][ni], 0, 0, 0);
            }
        __builtin_amdgcn_s_setprio(0);
    };

    stage(0, 0);
    asm volatile("s_waitcnt vmcnt(0)" ::: "memory");
    __builtin_amdgcn_s_barrier();

    int cur = 0;
    for (int kt = 0; kt < H_ / 32 - 1; kt++) {
        const int base = cur * 6144;
        stage(kt + 1, base ^ 6144);
        compute(base);
        asm volatile("s_waitcnt vmcnt(0) lgkmcnt(0)" ::: "memory");
        __builtin_amdgcn_s_barrier();
        cur ^= 1;
    }
    compute(cur * 6144);

    const int cc = lane & 15;
    const int cr = (lane >> 4) * 4;
#pragma unroll
    for (int ni = 0; ni < 2; ni++) {
        const int gc = ni * 16 + cc;
        if (gc < OUT_) {
            const float bv = bo[gc];
#pragma unroll
            for (int mi = 0; mi < 2; mi++) {
#pragma unroll
                for (int r = 0; r < 4; r++) {
                    const int gr = bm + wave * 32 + mi * 16 + cr + r;
                    const int bb = gr >> 7, tl = gr & (TP_ - 1);
                    if (tl < TC_)
                        curo[((size_t)bb * T_ + t0 + tl) * OUT_ + gc] = acc[mi][ni][r] + bv;
                }
            }
        }
    }
}

// ---------------- parallel readout: segmented scan + t-parallel softmax-sum ----------------
#define RT_SEG 12
#define RT_LEN 21   // 12*21 = 252 >= 250

__global__ __launch_bounds__(256)
void readout_kernel(const float* __restrict__ curo, const float* __restrict__ tau_mo,
                    float* __restrict__ out) {
    __shared__ float moS[T_ * OUT_];          // 20 KB
    __shared__ float segA[RT_SEG][OUT_];
    __shared__ float segU[RT_SEG][OUT_];
    __shared__ float pre[RT_SEG][OUT_];
    __shared__ float accS[OUT_];
    const int b = blockIdx.x;
    const int tid = threadIdx.x;
    const float* cb = curo + (size_t)b * T_ * OUT_;

    const int o = tid % OUT_;
    const int sg = tid / OUT_;
    const float ao = 1.f / (1.f + expf(-tau_mo[o]));

    if (tid < RT_SEG * OUT_) {
        int t0 = sg * RT_LEN;
        int t1 = min(T_, t0 + RT_LEN);
        float u = 0.f, Ap = 1.f;
        for (int t = t0; t < t1; t++) {
            u = ao * u + (1.f - ao) * cb[t * OUT_ + o];
            Ap *= ao;
        }
        segU[sg][o] = u; segA[sg][o] = Ap;
    }
    if (tid < OUT_) accS[tid] = 0.f;
    __syncthreads();
    if (tid < OUT_) {
        float m = 0.f;
        for (int s = 0; s < RT_SEG; s++) {
            pre[s][tid] = m;
            m = segA[s][tid] * m + segU[s][tid];
        }
    }
    __syncthreads();
    if (tid < RT_SEG * OUT_) {
        int t0 = sg * RT_LEN;
        int t1 = min(T_, t0 + RT_LEN);
        float m = pre[sg][o];
        for (int t = t0; t < t1; t++) {
            m = ao * m + (1.f - ao) * cb[t * OUT_ + o];
            moS[t * OUT_ + o] = m;
        }
    }
    __syncthreads();
    if (tid >= WARM_ + 1 && tid < T_) {
        int t = tid;
        float mx = -3.0e38f;
#pragma unroll
        for (int o2 = 0; o2 < OUT_; o2++) mx = fmaxf(mx, moS[t * OUT_ + o2]);
        float es[OUT_]; float se = 0.f;
#pragma unroll
        for (int o2 = 0; o2 < OUT_; o2++) {
            float e = expf(moS[t * OUT_ + o2] - mx);
            es[o2] = e; se += e;
        }
        float inv = 1.f / se;
#pragma unroll
        for (int o2 = 0; o2 < OUT_; o2++) atomicAdd(&accS[o2], es[o2] * inv);
    }
    __syncthreads();
    if (tid < OUT_) out[(size_t)b * OUT_ + tid] = accS[tid];
}

extern "C" void kernel_launch(void* const* d_in, const int* in_sizes, int n_in,
                              void* d_out, int out_size, void* d_ws, size_t ws_size,
                              hipStream_t stream) {
    const float* x      = (const float*)d_in[0];
    const float* W1     = (const float*)d_in[1];
    const float* b1     = (const float*)d_in[2];
    const float* tau_m1 = (const float*)d_in[3];
    const float* tau_n1 = (const float*)d_in[4];
    const float* mask1  = (const float*)d_in[5];
    const float* W2     = (const float*)d_in[6];
    const float* b2     = (const float*)d_in[7];
    const float* tau_m2 = (const float*)d_in[8];
    const float* tau_n2 = (const float*)d_in[9];
    const float* mask2  = (const float*)d_in[10];
    const float* Wo     = (const float*)d_in[11];
    const float* bo     = (const float*)d_in[12];
    const float* tau_mo = (const float*)d_in[13];
    float* out = (float*)d_out;

    // Fused-scan design: always 2 chunks of 125 timesteps (padded to 128).
    // Footprint ~86 MB (cur buffer eliminated).
    char* p = (char*)d_ws;
    auto alloc = [&](size_t bytes) { char* r = p; p += (bytes + 255) & ~(size_t)255; return r; };
    _Float16* w10 = (_Float16*)alloc((size_t)HB_ * INP_ * 2);
    _Float16* w11 = (_Float16*)alloc((size_t)HB_ * INP_ * 2);
    int8_t*   q2  = (int8_t*)alloc((size_t)HB_ * H_);
    int8_t*   q1  = (int8_t*)alloc((size_t)HB_ * H_);
    int8_t*   q0  = (int8_t*)alloc((size_t)HB_ * H_);
    _Float16* wo0 = (_Float16*)alloc((size_t)32 * H_ * 2);
    _Float16* wo1 = (_Float16*)alloc((size_t)32 * H_ * 2);
    _Float16* xc0 = (_Float16*)alloc((size_t)MP_ * INP_ * 2);
    _Float16* xc1 = (_Float16*)alloc((size_t)MP_ * INP_ * 2);
    int8_t*   s1c = (int8_t*)alloc((size_t)MP_ * H_);
    _Float16* s2c = (_Float16*)alloc((size_t)MP_ * H_ * 2);
    float* curo   = (float*)alloc((size_t)B_ * T_ * OUT_ * 4);
    float* st     = (float*)alloc((size_t)786432 * 4);
    float* d1  = st;
    float* m1  = d1 + (size_t)B_ * H_ * BR_;
    float* sp1 = m1 + (size_t)B_ * H_;
    float* d2  = sp1 + (size_t)B_ * H_;
    float* m2  = d2 + (size_t)B_ * H_ * BR_;
    float* sp2 = m2 + (size_t)B_ * H_;

    w1prep_kernel<<<(HB_ * INP_ + 255) / 256, 256, 0, stream>>>(W1, mask1, w10, w11);
    w2prep_kernel<<<(HB_ * H_ + 255) / 256, 256, 0, stream>>>(W2, mask2, q2, q1, q0);
    woprep_kernel<<<(32 * H_ + 255) / 256, 256, 0, stream>>>(Wo, wo0, wo1);
    zero_kernel<<<(786432 / 4 + 255) / 256, 256, 0, stream>>>(st, 786432 / 4);

    dim3 gg(HB_ / 128, B_);                 // (16 n-tiles, 128 batches)
    for (int c = 0; c < 2; c++) {
        const int t0 = c * TC_;
        convx_kernel<<<(MP_ * INP_) / 256, 256, 0, stream>>>(x, xc0, xc1, t0);
        l1_fused_kernel<<<gg, 256, 0, stream>>>(xc0, xc1, w10, w11, b1,
                                                d1, m1, sp1, s1c, tau_m1, tau_n1);
        l2_fused_kernel<<<gg, 256, 0, stream>>>(s1c, q2, q1, q0, b2,
                                                d2, m2, sp2, s2c, tau_m2, tau_n2);
        rdot_mfma_kernel<<<MP_ / 128, 256, 0, stream>>>(s2c, wo0, wo1, bo, curo, t0);
    }
    readout_kernel<<<B_, 256, 0, stream>>>(curo, tau_mo, out);
}